// Round 2
// baseline (5635.975 us; speedup 1.0000x reference)
//
#include <hip/hip_runtime.h>

#define N_NODES 100000
#define DIM 128

// ---------------------------------------------------------------------------
// Scatter-add: h[dst] += x[src].  32 consecutive lanes handle one edge,
// each lane a float4 (32*4 = 128 floats). Grid-stride, stride multiple of 32.
// Note: edge_index arrives as int32 (harness converts integer inputs).
// ---------------------------------------------------------------------------
__global__ __launch_bounds__(256) void scatter_kernel(
    const float* __restrict__ x, const int* __restrict__ ei,
    float* __restrict__ h, int E_) {
  long long total = (long long)E_ * 32;
  long long stride = (long long)gridDim.x * blockDim.x;
  for (long long idx = (long long)blockIdx.x * blockDim.x + threadIdx.x;
       idx < total; idx += stride) {
    int e = (int)(idx >> 5);
    int q = (int)(idx & 31);
    int src = ei[e];
    int dst = ei[E_ + e];
    float4 v = *reinterpret_cast<const float4*>(x + (size_t)src * DIM + q * 4);
    float* p = h + (size_t)dst * DIM + q * 4;
    atomicAdd(p + 0, v.x);
    atomicAdd(p + 1, v.y);
    atomicAdd(p + 2, v.z);
    atomicAdd(p + 3, v.w);
  }
}

// ---------------------------------------------------------------------------
// Fused MLP, in place on hbuf: reads h = x + hbuf (hbuf holds agg), computes
// relu((relu(h@W1+b1))@W2+b2), writes back to the same 32 rows of hbuf.
// Each block owns rows [32b, 32b+32); reads them into LDS before writing.
// ---------------------------------------------------------------------------
__global__ __launch_bounds__(256) void mlp_kernel(
    const float* __restrict__ x, float* hbuf, const float* __restrict__ W1,
    const float* __restrict__ b1, const float* __restrict__ W2,
    const float* __restrict__ b2) {
  __shared__ float sW[DIM * DIM];  // 64 KB, W1 then W2
  __shared__ float sH[32][DIM];    // 16 KB, h then h1
  const int tid = threadIdx.x;
  const int col = tid & 127;
  const int rhalf = tid >> 7;  // 0 or 1
  const int row0 = blockIdx.x * 32;

  for (int i = tid; i < DIM * DIM; i += 256) sW[i] = W1[i];
  for (int i = tid; i < 32 * DIM; i += 256) {
    int r = i >> 7, c = i & 127;
    size_t g = (size_t)(row0 + r) * DIM + c;
    sH[r][c] = x[g] + hbuf[g];
  }
  __syncthreads();

  float acc[16];
  {
    float bias = b1[col];
#pragma unroll
    for (int j = 0; j < 16; ++j) acc[j] = bias;
  }
#pragma unroll 4
  for (int k = 0; k < DIM; ++k) {
    float w = sW[k * DIM + col];
#pragma unroll
    for (int j = 0; j < 16; ++j) acc[j] = fmaf(sH[2 * j + rhalf][k], w, acc[j]);
  }
  __syncthreads();
  // Overwrite sW with W2 and sH with relu(h1)
  for (int i = tid; i < DIM * DIM; i += 256) sW[i] = W2[i];
#pragma unroll
  for (int j = 0; j < 16; ++j) sH[2 * j + rhalf][col] = fmaxf(acc[j], 0.f);
  __syncthreads();

  {
    float bias2 = b2[col];
#pragma unroll
    for (int j = 0; j < 16; ++j) acc[j] = bias2;
  }
#pragma unroll 4
  for (int k = 0; k < DIM; ++k) {
    float w = sW[k * DIM + col];
#pragma unroll
    for (int j = 0; j < 16; ++j) acc[j] = fmaf(sH[2 * j + rhalf][k], w, acc[j]);
  }
#pragma unroll
  for (int j = 0; j < 16; ++j) {
    hbuf[(size_t)(row0 + 2 * j + rhalf) * DIM + col] = fmaxf(acc[j], 0.f);
  }
}

// ---------------------------------------------------------------------------
// BN stats: per-column sum and sum-of-squares over N rows.
// ---------------------------------------------------------------------------
__global__ __launch_bounds__(256) void bn_stats_kernel(
    const float* __restrict__ h, float* __restrict__ stats) {
  int col = threadIdx.x & 127;
  int rsub = threadIdx.x >> 7;
  int rstep = gridDim.x * 2;
  float s = 0.f, ss = 0.f;
  for (int r = blockIdx.x * 2 + rsub; r < N_NODES; r += rstep) {
    float v = h[(size_t)r * DIM + col];
    s += v;
    ss += v * v;
  }
  __shared__ float ls[256], lss[256];
  ls[threadIdx.x] = s;
  lss[threadIdx.x] = ss;
  __syncthreads();
  if (threadIdx.x < 128) {
    atomicAdd(&stats[col], ls[threadIdx.x] + ls[threadIdx.x + 128]);
    atomicAdd(&stats[DIM + col], lss[threadIdx.x] + lss[threadIdx.x + 128]);
  }
}

__global__ void bn_scale_kernel(const float* __restrict__ stats,
                                const float* __restrict__ gamma,
                                const float* __restrict__ beta,
                                float* __restrict__ sc) {
  int c = threadIdx.x;  // 128 threads
  float mean = stats[c] / (float)N_NODES;
  float var = stats[DIM + c] / (float)N_NODES - mean * mean;
  float scale = gamma[c] * rsqrtf(var + 1e-5f);
  sc[c] = scale;
  sc[DIM + c] = beta[c] - mean * scale;
}

__global__ __launch_bounds__(256) void bn_apply_kernel(
    float* __restrict__ h, const float* __restrict__ sc) {
  size_t total = (size_t)N_NODES * DIM / 4;
  size_t stride = (size_t)gridDim.x * blockDim.x;
  for (size_t i = (size_t)blockIdx.x * blockDim.x + threadIdx.x; i < total;
       i += stride) {
    float4 v = reinterpret_cast<float4*>(h)[i];
    int c = (int)((i * 4) & 127);
    v.x = v.x * sc[c + 0] + sc[DIM + c + 0];
    v.y = v.y * sc[c + 1] + sc[DIM + c + 1];
    v.z = v.z * sc[c + 2] + sc[DIM + c + 2];
    v.w = v.w * sc[c + 3] + sc[DIM + c + 3];
    reinterpret_cast<float4*>(h)[i] = v;
  }
}

extern "C" void kernel_launch(void* const* d_in, const int* in_sizes, int n_in,
                              void* d_out, int out_size, void* d_ws,
                              size_t ws_size, hipStream_t stream) {
  const float* x = (const float*)d_in[0];
  const int* ei = (const int*)d_in[1];  // harness converts int64 -> int32
  // d_in[2] = edge_attr, unused by the reference
  const float* W1 = (const float*)d_in[3];
  const float* b1 = (const float*)d_in[4];
  const float* W2 = (const float*)d_in[5];
  const float* b2 = (const float*)d_in[6];
  const float* gamma = (const float*)d_in[7];
  const float* beta = (const float*)d_in[8];
  float* out = (float*)d_out;      // doubles as the agg accumulator
  float* stats = (float*)d_ws;     // 768 floats of scratch
  int E_ = in_sizes[1] / 2;

  hipMemsetAsync(out, 0, (size_t)N_NODES * DIM * sizeof(float), stream);
  hipMemsetAsync(stats, 0, 768 * sizeof(float), stream);
  scatter_kernel<<<4096, 256, 0, stream>>>(x, ei, out, E_);
  mlp_kernel<<<(N_NODES + 31) / 32, 256, 0, stream>>>(x, out, W1, b1, W2, b2);
  bn_stats_kernel<<<1024, 256, 0, stream>>>(out, stats);
  bn_scale_kernel<<<1, 128, 0, stream>>>(stats, gamma, beta, stats + 256);
  bn_apply_kernel<<<2048, 256, 0, stream>>>(out, stats + 256);
}

// Round 3
// 997.062 us; speedup vs baseline: 5.6526x; 5.6526x over previous
//
#include <hip/hip_runtime.h>

#define N_NODES 100000
#define DIM 128

// ======================= CSR build =======================
__global__ __launch_bounds__(256) void hist_kernel(const int* __restrict__ ei,
                                                   int* __restrict__ deg,
                                                   int E_) {
  int stride = gridDim.x * blockDim.x;
  for (int e = blockIdx.x * blockDim.x + threadIdx.x; e < E_; e += stride)
    atomicAdd(&deg[ei[E_ + e]], 1);
}

// Block-level exclusive scan: each block scans 1024 elements (4/thread),
// writes per-block-exclusive results to offs and the block total to partials.
__global__ __launch_bounds__(256) void scan_block_kernel(
    const int* __restrict__ deg, int* __restrict__ offs,
    int* __restrict__ partials, int n) {
  const int tid = threadIdx.x;
  int g = blockIdx.x * 1024 + tid * 4;
  int v0 = (g + 0 < n) ? deg[g + 0] : 0;
  int v1 = (g + 1 < n) ? deg[g + 1] : 0;
  int v2 = (g + 2 < n) ? deg[g + 2] : 0;
  int v3 = (g + 3 < n) ? deg[g + 3] : 0;
  int tsum = v0 + v1 + v2 + v3;
  __shared__ int s[256];
  s[tid] = tsum;
  __syncthreads();
  for (int off = 1; off < 256; off <<= 1) {
    int t = (tid >= off) ? s[tid - off] : 0;
    __syncthreads();
    s[tid] += t;
    __syncthreads();
  }
  int excl = s[tid] - tsum;  // exclusive prefix within block
  if (g + 0 < n) offs[g + 0] = excl;
  if (g + 1 < n) offs[g + 1] = excl + v0;
  if (g + 2 < n) offs[g + 2] = excl + v0 + v1;
  if (g + 3 < n) offs[g + 3] = excl + v0 + v1 + v2;
  if (tid == 255) partials[blockIdx.x] = s[255];
}

__global__ void scan_partials_kernel(int* __restrict__ partials, int nb) {
  const int tid = threadIdx.x;  // 128 threads, nb <= 128
  int v = (tid < nb) ? partials[tid] : 0;
  __shared__ int s[128];
  s[tid] = v;
  __syncthreads();
  for (int off = 1; off < 128; off <<= 1) {
    int t = (tid >= off) ? s[tid - off] : 0;
    __syncthreads();
    s[tid] += t;
    __syncthreads();
  }
  if (tid < nb) partials[tid] = s[tid] - v;  // exclusive
}

__global__ __launch_bounds__(256) void scan_add_kernel(
    int* __restrict__ offs, int* __restrict__ cursor,
    const int* __restrict__ partials, int n, int E_) {
  int g = blockIdx.x * blockDim.x + threadIdx.x;
  if (g < n) {
    int v = offs[g] + partials[g >> 10];
    offs[g] = v;
    cursor[g] = v;
  }
  if (g == 0) offs[n] = E_;
}

__global__ __launch_bounds__(256) void fill_kernel(const int* __restrict__ ei,
                                                   int* __restrict__ cursor,
                                                   int* __restrict__ csr,
                                                   int E_) {
  int stride = gridDim.x * blockDim.x;
  for (int e = blockIdx.x * blockDim.x + threadIdx.x; e < E_; e += stride) {
    int pos = atomicAdd(&cursor[ei[E_ + e]], 1);
    csr[pos] = ei[e];  // src
  }
}

// ======================= Gather: h = x + sum_{j->n} x_j =======================
__global__ __launch_bounds__(128) void gather_kernel(
    const float* __restrict__ x, const int* __restrict__ offs,
    const int* __restrict__ csr, float* __restrict__ h) {
  int n = blockIdx.x;
  int c = threadIdx.x;
  int beg = offs[n], end = offs[n + 1];
  float acc = x[(size_t)n * DIM + c];
  for (int j = beg; j < end; ++j) {
    int src = csr[j];  // uniform across block -> broadcast load
    acc += x[(size_t)src * DIM + c];
  }
  h[(size_t)n * DIM + c] = acc;
}

// ======================= Fallback atomic scatter =======================
__global__ __launch_bounds__(256) void scatter_kernel(
    const float* __restrict__ x, const int* __restrict__ ei,
    float* __restrict__ h, int E_) {
  long long total = (long long)E_ * 32;
  long long stride = (long long)gridDim.x * blockDim.x;
  for (long long idx = (long long)blockIdx.x * blockDim.x + threadIdx.x;
       idx < total; idx += stride) {
    int e = (int)(idx >> 5);
    int q = (int)(idx & 31);
    int src = ei[e];
    int dst = ei[E_ + e];
    float4 v = *reinterpret_cast<const float4*>(x + (size_t)src * DIM + q * 4);
    float* p = h + (size_t)dst * DIM + q * 4;
    atomicAdd(p + 0, v.x);
    atomicAdd(p + 1, v.y);
    atomicAdd(p + 2, v.z);
    atomicAdd(p + 3, v.w);
  }
}

__global__ __launch_bounds__(256) void add_x_kernel(const float* __restrict__ x,
                                                    float* __restrict__ h) {
  size_t total = (size_t)N_NODES * DIM / 4;
  size_t stride = (size_t)gridDim.x * blockDim.x;
  for (size_t i = (size_t)blockIdx.x * blockDim.x + threadIdx.x; i < total;
       i += stride) {
    float4 v = reinterpret_cast<float4*>(h)[i];
    float4 xv = reinterpret_cast<const float4*>(x)[i];
    v.x += xv.x; v.y += xv.y; v.z += xv.z; v.w += xv.w;
    reinterpret_cast<float4*>(h)[i] = v;
  }
}

// ======================= MLP (in place on hbuf) =======================
// hbuf holds h = x + agg; computes relu((relu(h@W1+b1))@W2+b2) back into hbuf.
__global__ __launch_bounds__(256) void mlp_kernel(float* hbuf,
                                                  const float* __restrict__ W1,
                                                  const float* __restrict__ b1,
                                                  const float* __restrict__ W2,
                                                  const float* __restrict__ b2) {
  __shared__ float sW[DIM * DIM];  // 64 KB, W1 then W2
  __shared__ float sH[32][DIM];    // 16 KB, h then h1
  const int tid = threadIdx.x;
  const int col = tid & 127;
  const int rhalf = tid >> 7;
  const int row0 = blockIdx.x * 32;

  for (int i = tid; i < DIM * DIM; i += 256) sW[i] = W1[i];
  for (int i = tid; i < 32 * DIM; i += 256) {
    int r = i >> 7, c = i & 127;
    sH[r][c] = hbuf[(size_t)(row0 + r) * DIM + c];
  }
  __syncthreads();

  float acc[16];
  {
    float bias = b1[col];
#pragma unroll
    for (int j = 0; j < 16; ++j) acc[j] = bias;
  }
#pragma unroll 4
  for (int k = 0; k < DIM; ++k) {
    float w = sW[k * DIM + col];
#pragma unroll
    for (int j = 0; j < 16; ++j) acc[j] = fmaf(sH[2 * j + rhalf][k], w, acc[j]);
  }
  __syncthreads();
  for (int i = tid; i < DIM * DIM; i += 256) sW[i] = W2[i];
#pragma unroll
  for (int j = 0; j < 16; ++j) sH[2 * j + rhalf][col] = fmaxf(acc[j], 0.f);
  __syncthreads();

  {
    float bias2 = b2[col];
#pragma unroll
    for (int j = 0; j < 16; ++j) acc[j] = bias2;
  }
#pragma unroll 4
  for (int k = 0; k < DIM; ++k) {
    float w = sW[k * DIM + col];
#pragma unroll
    for (int j = 0; j < 16; ++j) acc[j] = fmaf(sH[2 * j + rhalf][k], w, acc[j]);
  }
#pragma unroll
  for (int j = 0; j < 16; ++j) {
    hbuf[(size_t)(row0 + 2 * j + rhalf) * DIM + col] = fmaxf(acc[j], 0.f);
  }
}

// ======================= BatchNorm =======================
__global__ __launch_bounds__(256) void bn_stats_kernel(
    const float* __restrict__ h, float* __restrict__ stats) {
  int col = threadIdx.x & 127;
  int rsub = threadIdx.x >> 7;
  int rstep = gridDim.x * 2;
  float s = 0.f, ss = 0.f;
  for (int r = blockIdx.x * 2 + rsub; r < N_NODES; r += rstep) {
    float v = h[(size_t)r * DIM + col];
    s += v;
    ss += v * v;
  }
  __shared__ float ls[256], lss[256];
  ls[threadIdx.x] = s;
  lss[threadIdx.x] = ss;
  __syncthreads();
  if (threadIdx.x < 128) {
    atomicAdd(&stats[col], ls[threadIdx.x] + ls[threadIdx.x + 128]);
    atomicAdd(&stats[DIM + col], lss[threadIdx.x] + lss[threadIdx.x + 128]);
  }
}

__global__ void bn_scale_kernel(const float* __restrict__ stats,
                                const float* __restrict__ gamma,
                                const float* __restrict__ beta,
                                float* __restrict__ sc) {
  int c = threadIdx.x;  // 128 threads
  float mean = stats[c] / (float)N_NODES;
  float var = stats[DIM + c] / (float)N_NODES - mean * mean;
  float scale = gamma[c] * rsqrtf(var + 1e-5f);
  sc[c] = scale;
  sc[DIM + c] = beta[c] - mean * scale;
}

__global__ __launch_bounds__(256) void bn_apply_kernel(
    float* __restrict__ h, const float* __restrict__ sc) {
  size_t total = (size_t)N_NODES * DIM / 4;
  size_t stride = (size_t)gridDim.x * blockDim.x;
  for (size_t i = (size_t)blockIdx.x * blockDim.x + threadIdx.x; i < total;
       i += stride) {
    float4 v = reinterpret_cast<float4*>(h)[i];
    int c = (int)((i * 4) & 127);
    v.x = v.x * sc[c + 0] + sc[DIM + c + 0];
    v.y = v.y * sc[c + 1] + sc[DIM + c + 1];
    v.z = v.z * sc[c + 2] + sc[DIM + c + 2];
    v.w = v.w * sc[c + 3] + sc[DIM + c + 3];
    reinterpret_cast<float4*>(h)[i] = v;
  }
}

extern "C" void kernel_launch(void* const* d_in, const int* in_sizes, int n_in,
                              void* d_out, int out_size, void* d_ws,
                              size_t ws_size, hipStream_t stream) {
  const float* x = (const float*)d_in[0];
  const int* ei = (const int*)d_in[1];  // harness converts int64 -> int32
  const float* W1 = (const float*)d_in[3];
  const float* b1 = (const float*)d_in[4];
  const float* W2 = (const float*)d_in[5];
  const float* b2 = (const float*)d_in[6];
  const float* gamma = (const float*)d_in[7];
  const float* beta = (const float*)d_in[8];
  float* out = (float*)d_out;  // h buffer
  int E_ = in_sizes[1] / 2;

  // Workspace layout (ints): offs[N+1] | cursor[N] | partials[128] | csr[E]
  // then stats: float[768]
  size_t need = ((size_t)(N_NODES + 1) + N_NODES + 128 + (size_t)E_) * 4 +
                768 * sizeof(float);
  int* offs = (int*)d_ws;
  int* cursor = offs + N_NODES + 1;
  int* partials = cursor + N_NODES;
  int* csr = partials + 128;
  float* stats = (float*)(csr + E_);

  const int nScanBlocks = (N_NODES + 1023) / 1024;  // 98

  if (ws_size >= need) {
    hipMemsetAsync(cursor, 0, (size_t)N_NODES * sizeof(int), stream);
    hipMemsetAsync(stats, 0, 768 * sizeof(float), stream);
    hist_kernel<<<2048, 256, 0, stream>>>(ei, cursor, E_);
    scan_block_kernel<<<nScanBlocks, 256, 0, stream>>>(cursor, offs, partials,
                                                       N_NODES);
    scan_partials_kernel<<<1, 128, 0, stream>>>(partials, nScanBlocks);
    scan_add_kernel<<<(N_NODES + 255) / 256, 256, 0, stream>>>(
        offs, cursor, partials, N_NODES, E_);
    fill_kernel<<<2048, 256, 0, stream>>>(ei, cursor, csr, E_);
    gather_kernel<<<N_NODES, 128, 0, stream>>>(x, offs, csr, out);
  } else {
    // Fallback: atomic scatter (correct, slower)
    float* stats2 = (float*)d_ws;
    stats = stats2;
    hipMemsetAsync(out, 0, (size_t)N_NODES * DIM * sizeof(float), stream);
    hipMemsetAsync(stats, 0, 768 * sizeof(float), stream);
    scatter_kernel<<<4096, 256, 0, stream>>>(x, ei, out, E_);
    add_x_kernel<<<2048, 256, 0, stream>>>(x, out);
  }

  mlp_kernel<<<(N_NODES + 31) / 32, 256, 0, stream>>>(out, W1, b1, W2, b2);
  bn_stats_kernel<<<1024, 256, 0, stream>>>(out, stats);
  bn_scale_kernel<<<1, 128, 0, stream>>>(stats, gamma, beta, stats + 256);
  bn_apply_kernel<<<2048, 256, 0, stream>>>(out, stats + 256);
}

// Round 4
// 763.891 us; speedup vs baseline: 7.3780x; 1.3052x over previous
//
#include <hip/hip_runtime.h>

#define N_NODES 100000
#define DIM 128

typedef unsigned int u32;
typedef unsigned short u16;
typedef __attribute__((ext_vector_type(8))) short bf16x8;
typedef __attribute__((ext_vector_type(4))) float f32x4;

__device__ __forceinline__ float bf16_to_f(u16 v) {
  return __uint_as_float(((u32)v) << 16);
}
__device__ __forceinline__ u16 f_to_bf16(float f) {
  u32 b = __float_as_uint(f);
  b += 0x7fff + ((b >> 16) & 1);  // round-to-nearest-even
  return (u16)(b >> 16);
}

// ======================= prep: conversions =======================
__global__ __launch_bounds__(256) void cvt_x_kernel(const float* __restrict__ x,
                                                    u16* __restrict__ xb) {
  int total = N_NODES * DIM / 4;
  int stride = gridDim.x * blockDim.x;
  for (int i = blockIdx.x * blockDim.x + threadIdx.x; i < total; i += stride) {
    float4 v = reinterpret_cast<const float4*>(x)[i];
    ushort4 o;
    o.x = f_to_bf16(v.x);
    o.y = f_to_bf16(v.y);
    o.z = f_to_bf16(v.z);
    o.w = f_to_bf16(v.w);
    reinterpret_cast<ushort4*>(xb)[i] = o;
  }
}

// Wt[c][k] = bf16(W[k][c]) : B^T image, k-contiguous for MFMA B-fragments.
__global__ void cvt_w_kernel(const float* __restrict__ W, u16* __restrict__ Wt) {
  int id = blockIdx.x * 256 + threadIdx.x;  // id = c*128 + k
  int c = id >> 7, k = id & 127;
  Wt[id] = f_to_bf16(W[k * DIM + c]);
}

// ======================= CSR build =======================
__global__ __launch_bounds__(256) void hist_kernel(const int* __restrict__ ei,
                                                   int* __restrict__ deg,
                                                   int E_) {
  int stride = gridDim.x * blockDim.x;
  for (int e = blockIdx.x * blockDim.x + threadIdx.x; e < E_; e += stride)
    atomicAdd(&deg[ei[E_ + e]], 1);
}

__global__ __launch_bounds__(256) void scan_block_kernel(
    const int* __restrict__ deg, int* __restrict__ offs,
    int* __restrict__ partials, int n) {
  const int tid = threadIdx.x;
  int g = blockIdx.x * 1024 + tid * 4;
  int v0 = (g + 0 < n) ? deg[g + 0] : 0;
  int v1 = (g + 1 < n) ? deg[g + 1] : 0;
  int v2 = (g + 2 < n) ? deg[g + 2] : 0;
  int v3 = (g + 3 < n) ? deg[g + 3] : 0;
  int tsum = v0 + v1 + v2 + v3;
  __shared__ int s[256];
  s[tid] = tsum;
  __syncthreads();
  for (int off = 1; off < 256; off <<= 1) {
    int t = (tid >= off) ? s[tid - off] : 0;
    __syncthreads();
    s[tid] += t;
    __syncthreads();
  }
  int excl = s[tid] - tsum;
  if (g + 0 < n) offs[g + 0] = excl;
  if (g + 1 < n) offs[g + 1] = excl + v0;
  if (g + 2 < n) offs[g + 2] = excl + v0 + v1;
  if (g + 3 < n) offs[g + 3] = excl + v0 + v1 + v2;
  if (tid == 255) partials[blockIdx.x] = s[255];
}

__global__ void scan_partials_kernel(int* __restrict__ partials, int nb) {
  const int tid = threadIdx.x;  // 128 threads, nb <= 128
  int v = (tid < nb) ? partials[tid] : 0;
  __shared__ int s[128];
  s[tid] = v;
  __syncthreads();
  for (int off = 1; off < 128; off <<= 1) {
    int t = (tid >= off) ? s[tid - off] : 0;
    __syncthreads();
    s[tid] += t;
    __syncthreads();
  }
  if (tid < nb) partials[tid] = s[tid] - v;
}

__global__ __launch_bounds__(256) void scan_add_kernel(
    int* __restrict__ offs, int* __restrict__ cursor,
    const int* __restrict__ partials, int n, int E_) {
  int g = blockIdx.x * blockDim.x + threadIdx.x;
  if (g < n) {
    int v = offs[g] + partials[g >> 10];
    offs[g] = v;
    cursor[g] = v;
  }
  if (g == 0) offs[n] = E_;
}

__global__ __launch_bounds__(256) void fill_kernel(const int* __restrict__ ei,
                                                   int* __restrict__ cursor,
                                                   int* __restrict__ csr,
                                                   int E_) {
  int stride = gridDim.x * blockDim.x;
  for (int e = blockIdx.x * blockDim.x + threadIdx.x; e < E_; e += stride) {
    int pos = atomicAdd(&cursor[ei[E_ + e]], 1);
    csr[pos] = ei[e];
  }
}

// ======================= Gather (bf16 rows, fp32 accum) ==================
// One wave per node; lane holds 2 columns packed in one u32.
__global__ __launch_bounds__(256) void gather_bf16_kernel(
    const u32* __restrict__ xb, const int* __restrict__ offs,
    const int* __restrict__ csr, u32* __restrict__ hb) {
  int n = blockIdx.x * 4 + (threadIdx.x >> 6);
  int lane = threadIdx.x & 63;
  int beg = offs[n], end = offs[n + 1];
  u32 p = xb[(size_t)n * 64 + lane];
  float a0 = bf16_to_f((u16)(p & 0xffff));
  float a1 = bf16_to_f((u16)(p >> 16));
  int j = beg;
  int srcNext = (j < end) ? csr[j] : 0;
  while (j < end) {
    int src = srcNext;
    ++j;
    if (j < end) srcNext = csr[j];  // prefetch next index
    u32 q = xb[(size_t)src * 64 + lane];
    a0 += bf16_to_f((u16)(q & 0xffff));
    a1 += bf16_to_f((u16)(q >> 16));
  }
  hb[(size_t)n * 64 + lane] = ((u32)f_to_bf16(a1) << 16) | (u32)f_to_bf16(a0);
}

// ======================= MFMA MLP =======================
// Block = 256 threads (4 waves), 64 rows/block (16 per wave).
// Layer L: out[r][c] = sum_k in[r][k] * Wt[c][k]  (Wt = W^T, bf16).
// A-frags direct from global hb; B-frags direct from global Wt (L1/L2-hot).
// Layer1 -> layer2 relay via per-wave 4KB swizzled LDS slab.
__global__ __launch_bounds__(256) void mlp_mfma_kernel(
    const u16* __restrict__ hb, const u16* __restrict__ Wt1,
    const u16* __restrict__ Wt2, const float* __restrict__ b1,
    const float* __restrict__ b2, float* __restrict__ out) {
  __shared__ u16 sH1[4][16 * DIM];  // 16 KB total, per-wave slab
  const int tid = threadIdx.x;
  const int wv = tid >> 6;
  const int lane = tid & 63;
  const int lr = lane & 15;  // A-row / B-col / C-col index
  const int lq = lane >> 4;  // 0..3
  const int row0 = blockIdx.x * 64 + wv * 16;

  // ---- layer 1 ----
  bf16x8 a[4];
  {
    int r = row0 + lr;
    if (r > N_NODES - 1) r = N_NODES - 1;  // tail clamp (stores masked later)
#pragma unroll
    for (int ks = 0; ks < 4; ++ks)
      a[ks] = *reinterpret_cast<const bf16x8*>(hb + (size_t)r * DIM + ks * 32 +
                                               lq * 8);
  }
  f32x4 acc[8];
#pragma unroll
  for (int ct = 0; ct < 8; ++ct) {
    f32x4 c = {0.f, 0.f, 0.f, 0.f};
#pragma unroll
    for (int ks = 0; ks < 4; ++ks) {
      bf16x8 b = *reinterpret_cast<const bf16x8*>(
          Wt1 + (ct * 16 + lr) * DIM + ks * 32 + lq * 8);
      c = __builtin_amdgcn_mfma_f32_16x16x32_bf16(a[ks], b, c, 0, 0, 0);
    }
    acc[ct] = c;
  }
  // bias + relu -> bf16 -> swizzled LDS slab
  char* slab = reinterpret_cast<char*>(&sH1[wv][0]);
#pragma unroll
  for (int ct = 0; ct < 8; ++ct) {
    int c = ct * 16 + lr;
    float bias = b1[c];
#pragma unroll
    for (int j = 0; j < 4; ++j) {
      int rl = lq * 4 + j;  // C/D row = (lane>>4)*4 + reg
      float y = fmaxf(acc[ct][j] + bias, 0.f);
      int byte = rl * 256 + ((c * 2) ^ ((rl & 7) << 4));
      *reinterpret_cast<u16*>(slab + byte) = f_to_bf16(y);
    }
  }
  __syncthreads();

  // ---- layer 2 ----
  bf16x8 a2[4];
#pragma unroll
  for (int ks = 0; ks < 4; ++ks) {
    int byte = lr * 256 + (((ks * 32 + lq * 8) * 2) ^ ((lr & 7) << 4));
    a2[ks] = *reinterpret_cast<const bf16x8*>(slab + byte);
  }
#pragma unroll
  for (int ct = 0; ct < 8; ++ct) {
    f32x4 c = {0.f, 0.f, 0.f, 0.f};
#pragma unroll
    for (int ks = 0; ks < 4; ++ks) {
      bf16x8 b = *reinterpret_cast<const bf16x8*>(
          Wt2 + (ct * 16 + lr) * DIM + ks * 32 + lq * 8);
      c = __builtin_amdgcn_mfma_f32_16x16x32_bf16(a2[ks], b, c, 0, 0, 0);
    }
    acc[ct] = c;
  }
#pragma unroll
  for (int ct = 0; ct < 8; ++ct) {
    int c = ct * 16 + lr;
    float bias = b2[c];
#pragma unroll
    for (int j = 0; j < 4; ++j) {
      int r = row0 + lq * 4 + j;
      if (r < N_NODES)
        out[(size_t)r * DIM + c] = fmaxf(acc[ct][j] + bias, 0.f);
    }
  }
}

// ======================= BatchNorm =======================
__global__ __launch_bounds__(256) void bn_stats_kernel(
    const float* __restrict__ h, float* __restrict__ stats) {
  int col = threadIdx.x & 127;
  int rsub = threadIdx.x >> 7;
  int rstep = gridDim.x * 2;
  float s = 0.f, ss = 0.f;
  for (int r = blockIdx.x * 2 + rsub; r < N_NODES; r += rstep) {
    float v = h[(size_t)r * DIM + col];
    s += v;
    ss += v * v;
  }
  __shared__ float ls[256], lss[256];
  ls[threadIdx.x] = s;
  lss[threadIdx.x] = ss;
  __syncthreads();
  if (threadIdx.x < 128) {
    atomicAdd(&stats[col], ls[threadIdx.x] + ls[threadIdx.x + 128]);
    atomicAdd(&stats[DIM + col], lss[threadIdx.x] + lss[threadIdx.x + 128]);
  }
}

__global__ void bn_scale_kernel(const float* __restrict__ stats,
                                const float* __restrict__ gamma,
                                const float* __restrict__ beta,
                                float* __restrict__ sc) {
  int c = threadIdx.x;  // 128
  float mean = stats[c] / (float)N_NODES;
  float var = stats[DIM + c] / (float)N_NODES - mean * mean;
  float scale = gamma[c] * rsqrtf(var + 1e-5f);
  sc[c] = scale;
  sc[DIM + c] = beta[c] - mean * scale;
}

__global__ __launch_bounds__(256) void bn_apply_kernel(
    float* __restrict__ h, const float* __restrict__ sc) {
  size_t total = (size_t)N_NODES * DIM / 4;
  size_t stride = (size_t)gridDim.x * blockDim.x;
  for (size_t i = (size_t)blockIdx.x * blockDim.x + threadIdx.x; i < total;
       i += stride) {
    float4 v = reinterpret_cast<float4*>(h)[i];
    int c = (int)((i * 4) & 127);
    v.x = v.x * sc[c + 0] + sc[DIM + c + 0];
    v.y = v.y * sc[c + 1] + sc[DIM + c + 1];
    v.z = v.z * sc[c + 2] + sc[DIM + c + 2];
    v.w = v.w * sc[c + 3] + sc[DIM + c + 3];
    reinterpret_cast<float4*>(h)[i] = v;
  }
}

// ======================= Fallback kernels (f32 paths) =======================
__global__ __launch_bounds__(128) void gather_f32_kernel(
    const float* __restrict__ x, const int* __restrict__ offs,
    const int* __restrict__ csr, float* __restrict__ h) {
  int n = blockIdx.x;
  int c = threadIdx.x;
  int beg = offs[n], end = offs[n + 1];
  float acc = x[(size_t)n * DIM + c];
  for (int j = beg; j < end; ++j) acc += x[(size_t)csr[j] * DIM + c];
  h[(size_t)n * DIM + c] = acc;
}

__global__ __launch_bounds__(256) void scatter_kernel(
    const float* __restrict__ x, const int* __restrict__ ei,
    float* __restrict__ h, int E_) {
  long long total = (long long)E_ * 32;
  long long stride = (long long)gridDim.x * blockDim.x;
  for (long long idx = (long long)blockIdx.x * blockDim.x + threadIdx.x;
       idx < total; idx += stride) {
    int e = (int)(idx >> 5);
    int q = (int)(idx & 31);
    float4 v =
        *reinterpret_cast<const float4*>(x + (size_t)ei[e] * DIM + q * 4);
    float* p = h + (size_t)ei[E_ + e] * DIM + q * 4;
    atomicAdd(p + 0, v.x);
    atomicAdd(p + 1, v.y);
    atomicAdd(p + 2, v.z);
    atomicAdd(p + 3, v.w);
  }
}

__global__ __launch_bounds__(256) void add_x_kernel(const float* __restrict__ x,
                                                    float* __restrict__ h) {
  size_t total = (size_t)N_NODES * DIM / 4;
  size_t stride = (size_t)gridDim.x * blockDim.x;
  for (size_t i = (size_t)blockIdx.x * blockDim.x + threadIdx.x; i < total;
       i += stride) {
    float4 v = reinterpret_cast<float4*>(h)[i];
    float4 xv = reinterpret_cast<const float4*>(x)[i];
    v.x += xv.x; v.y += xv.y; v.z += xv.z; v.w += xv.w;
    reinterpret_cast<float4*>(h)[i] = v;
  }
}

__global__ __launch_bounds__(256) void mlp_valu_kernel(
    float* hbuf, const float* __restrict__ W1, const float* __restrict__ b1,
    const float* __restrict__ W2, const float* __restrict__ b2) {
  __shared__ float sW[DIM * DIM];
  __shared__ float sH[32][DIM];
  const int tid = threadIdx.x;
  const int col = tid & 127;
  const int rhalf = tid >> 7;
  const int row0 = blockIdx.x * 32;

  for (int i = tid; i < DIM * DIM; i += 256) sW[i] = W1[i];
  for (int i = tid; i < 32 * DIM; i += 256) {
    int r = i >> 7, c = i & 127;
    sH[r][c] = hbuf[(size_t)(row0 + r) * DIM + c];
  }
  __syncthreads();
  float acc[16];
  float bias = b1[col];
#pragma unroll
  for (int j = 0; j < 16; ++j) acc[j] = bias;
#pragma unroll 4
  for (int k = 0; k < DIM; ++k) {
    float w = sW[k * DIM + col];
#pragma unroll
    for (int j = 0; j < 16; ++j) acc[j] = fmaf(sH[2 * j + rhalf][k], w, acc[j]);
  }
  __syncthreads();
  for (int i = tid; i < DIM * DIM; i += 256) sW[i] = W2[i];
#pragma unroll
  for (int j = 0; j < 16; ++j) sH[2 * j + rhalf][col] = fmaxf(acc[j], 0.f);
  __syncthreads();
  float bias2 = b2[col];
#pragma unroll
  for (int j = 0; j < 16; ++j) acc[j] = bias2;
#pragma unroll 4
  for (int k = 0; k < DIM; ++k) {
    float w = sW[k * DIM + col];
#pragma unroll
    for (int j = 0; j < 16; ++j) acc[j] = fmaf(sH[2 * j + rhalf][k], w, acc[j]);
  }
#pragma unroll
  for (int j = 0; j < 16; ++j)
    hbuf[(size_t)(row0 + 2 * j + rhalf) * DIM + col] = fmaxf(acc[j], 0.f);
}

extern "C" void kernel_launch(void* const* d_in, const int* in_sizes, int n_in,
                              void* d_out, int out_size, void* d_ws,
                              size_t ws_size, hipStream_t stream) {
  const float* x = (const float*)d_in[0];
  const int* ei = (const int*)d_in[1];
  const float* W1 = (const float*)d_in[3];
  const float* b1 = (const float*)d_in[4];
  const float* W2 = (const float*)d_in[5];
  const float* b2 = (const float*)d_in[6];
  const float* gamma = (const float*)d_in[7];
  const float* beta = (const float*)d_in[8];
  float* out = (float*)d_out;
  int E_ = in_sizes[1] / 2;

  // ---- full-path workspace layout (all 16B-aligned) ----
  const size_t XB_B = (size_t)N_NODES * DIM * 2;  // 25.6e6
  char* w = (char*)d_ws;
  u16* xb = (u16*)w;
  u16* hb = (u16*)(w + XB_B);
  u16* Wt1 = (u16*)(w + 2 * XB_B);
  u16* Wt2 = (u16*)(w + 2 * XB_B + 32768);
  int* offs = (int*)(w + 2 * XB_B + 65536);
  int* cursor = offs + N_NODES + 1;
  int* partials = cursor + N_NODES;
  int* csr = partials + 128;
  float* stats = (float*)(csr + E_);
  size_t need_full =
      2 * XB_B + 65536 + ((size_t)2 * N_NODES + 129 + E_) * 4 + 3072;

  // ---- CSR-only fallback layout ----
  int* f_offs = (int*)d_ws;
  int* f_cursor = f_offs + N_NODES + 1;
  int* f_partials = f_cursor + N_NODES;
  int* f_csr = f_partials + 128;
  float* f_stats = (float*)(f_csr + E_);
  size_t need_csr = ((size_t)2 * N_NODES + 129 + E_) * 4 + 3072;

  const int nScanBlocks = (N_NODES + 1023) / 1024;  // 98

  if (ws_size >= need_full) {
    cvt_x_kernel<<<2048, 256, 0, stream>>>(x, xb);
    cvt_w_kernel<<<64, 256, 0, stream>>>(W1, Wt1);
    cvt_w_kernel<<<64, 256, 0, stream>>>(W2, Wt2);
    hipMemsetAsync(cursor, 0, (size_t)N_NODES * sizeof(int), stream);
    hipMemsetAsync(stats, 0, 768 * sizeof(float), stream);
    hist_kernel<<<2048, 256, 0, stream>>>(ei, cursor, E_);
    scan_block_kernel<<<nScanBlocks, 256, 0, stream>>>(cursor, offs, partials,
                                                       N_NODES);
    scan_partials_kernel<<<1, 128, 0, stream>>>(partials, nScanBlocks);
    scan_add_kernel<<<(N_NODES + 255) / 256, 256, 0, stream>>>(
        offs, cursor, partials, N_NODES, E_);
    fill_kernel<<<2048, 256, 0, stream>>>(ei, cursor, csr, E_);
    gather_bf16_kernel<<<N_NODES / 4, 256, 0, stream>>>((const u32*)xb, offs,
                                                        csr, (u32*)hb);
    mlp_mfma_kernel<<<(N_NODES + 63) / 64, 256, 0, stream>>>(hb, Wt1, Wt2, b1,
                                                             b2, out);
    bn_stats_kernel<<<1024, 256, 0, stream>>>(out, stats);
    bn_scale_kernel<<<1, 128, 0, stream>>>(stats, gamma, beta, stats + 256);
    bn_apply_kernel<<<2048, 256, 0, stream>>>(out, stats + 256);
  } else if (ws_size >= need_csr) {
    hipMemsetAsync(f_cursor, 0, (size_t)N_NODES * sizeof(int), stream);
    hipMemsetAsync(f_stats, 0, 768 * sizeof(float), stream);
    hist_kernel<<<2048, 256, 0, stream>>>(ei, f_cursor, E_);
    scan_block_kernel<<<nScanBlocks, 256, 0, stream>>>(f_cursor, f_offs,
                                                       f_partials, N_NODES);
    scan_partials_kernel<<<1, 128, 0, stream>>>(f_partials, nScanBlocks);
    scan_add_kernel<<<(N_NODES + 255) / 256, 256, 0, stream>>>(
        f_offs, f_cursor, f_partials, N_NODES, E_);
    fill_kernel<<<2048, 256, 0, stream>>>(ei, f_cursor, f_csr, E_);
    gather_f32_kernel<<<N_NODES, 128, 0, stream>>>(x, f_offs, f_csr, out);
    mlp_valu_kernel<<<(N_NODES + 31) / 32, 256, 0, stream>>>(out, W1, b1, W2,
                                                             b2);
    bn_stats_kernel<<<1024, 256, 0, stream>>>(out, f_stats);
    bn_scale_kernel<<<1, 128, 0, stream>>>(f_stats, gamma, beta, f_stats + 256);
    bn_apply_kernel<<<2048, 256, 0, stream>>>(out, f_stats + 256);
  } else {
    float* s2 = (float*)d_ws;
    hipMemsetAsync(out, 0, (size_t)N_NODES * DIM * sizeof(float), stream);
    hipMemsetAsync(s2, 0, 768 * sizeof(float), stream);
    scatter_kernel<<<4096, 256, 0, stream>>>(x, ei, out, E_);
    add_x_kernel<<<2048, 256, 0, stream>>>(x, out);
    mlp_valu_kernel<<<(N_NODES + 31) / 32, 256, 0, stream>>>(out, W1, b1, W2,
                                                             b2);
    bn_stats_kernel<<<1024, 256, 0, stream>>>(out, s2);
    bn_scale_kernel<<<1, 128, 0, stream>>>(s2, gamma, beta, s2 + 256);
    bn_apply_kernel<<<2048, 256, 0, stream>>>(out, s2 + 256);
  }
}

// Round 5
// 666.677 us; speedup vs baseline: 8.4538x; 1.1458x over previous
//
#include <hip/hip_runtime.h>

#define N_NODES 100000
#define DIM 128

typedef unsigned int u32;
typedef unsigned short u16;
typedef __attribute__((ext_vector_type(8))) short bf16x8;
typedef __attribute__((ext_vector_type(4))) float f32x4;

__device__ __forceinline__ float bf16_to_f(u16 v) {
  return __uint_as_float(((u32)v) << 16);
}
__device__ __forceinline__ u16 f_to_bf16(float f) {
  u32 b = __float_as_uint(f);
  b += 0x7fff + ((b >> 16) & 1);  // round-to-nearest-even
  return (u16)(b >> 16);
}

// ======================= prep: conversions =======================
__global__ __launch_bounds__(256) void cvt_x_kernel(const float* __restrict__ x,
                                                    u16* __restrict__ xb) {
  int total = N_NODES * DIM / 4;
  int stride = gridDim.x * blockDim.x;
  for (int i = blockIdx.x * blockDim.x + threadIdx.x; i < total; i += stride) {
    float4 v = reinterpret_cast<const float4*>(x)[i];
    ushort4 o;
    o.x = f_to_bf16(v.x);
    o.y = f_to_bf16(v.y);
    o.z = f_to_bf16(v.z);
    o.w = f_to_bf16(v.w);
    reinterpret_cast<ushort4*>(xb)[i] = o;
  }
}

// Wt[c][k] = bf16(W[k][c]) : B^T image, k-contiguous for MFMA B-fragments.
__global__ void cvt_w_kernel(const float* __restrict__ W, u16* __restrict__ Wt) {
  int id = blockIdx.x * 256 + threadIdx.x;  // id = c*128 + k
  int c = id >> 7, k = id & 127;
  Wt[id] = f_to_bf16(W[k * DIM + c]);
}

// ======================= CSR build =======================
// 8-way batched histogram: independent fire-and-forget atomics.
__global__ __launch_bounds__(256) void hist_kernel(const int* __restrict__ ei,
                                                   int* __restrict__ deg,
                                                   int E_) {
  const int G = gridDim.x * blockDim.x;
  int g = blockIdx.x * blockDim.x + threadIdx.x;
  for (long long base = g; base < E_; base += (long long)G * 8) {
    int d[8];
#pragma unroll
    for (int k = 0; k < 8; ++k) {
      long long e = base + (long long)k * G;
      d[k] = (e < E_) ? ei[E_ + e] : -1;
    }
#pragma unroll
    for (int k = 0; k < 8; ++k)
      if (d[k] >= 0) atomicAdd(&deg[d[k]], 1);
  }
}

__global__ __launch_bounds__(256) void scan_block_kernel(
    const int* __restrict__ deg, int* __restrict__ offs,
    int* __restrict__ partials, int n) {
  const int tid = threadIdx.x;
  int g = blockIdx.x * 1024 + tid * 4;
  int v0 = (g + 0 < n) ? deg[g + 0] : 0;
  int v1 = (g + 1 < n) ? deg[g + 1] : 0;
  int v2 = (g + 2 < n) ? deg[g + 2] : 0;
  int v3 = (g + 3 < n) ? deg[g + 3] : 0;
  int tsum = v0 + v1 + v2 + v3;
  __shared__ int s[256];
  s[tid] = tsum;
  __syncthreads();
  for (int off = 1; off < 256; off <<= 1) {
    int t = (tid >= off) ? s[tid - off] : 0;
    __syncthreads();
    s[tid] += t;
    __syncthreads();
  }
  int excl = s[tid] - tsum;
  if (g + 0 < n) offs[g + 0] = excl;
  if (g + 1 < n) offs[g + 1] = excl + v0;
  if (g + 2 < n) offs[g + 2] = excl + v0 + v1;
  if (g + 3 < n) offs[g + 3] = excl + v0 + v1 + v2;
  if (tid == 255) partials[blockIdx.x] = s[255];
}

__global__ void scan_partials_kernel(int* __restrict__ partials, int nb) {
  const int tid = threadIdx.x;  // 128 threads, nb <= 128
  int v = (tid < nb) ? partials[tid] : 0;
  __shared__ int s[128];
  s[tid] = v;
  __syncthreads();
  for (int off = 1; off < 128; off <<= 1) {
    int t = (tid >= off) ? s[tid - off] : 0;
    __syncthreads();
    s[tid] += t;
    __syncthreads();
  }
  if (tid < nb) partials[tid] = s[tid] - v;
}

__global__ __launch_bounds__(256) void scan_add_kernel(
    int* __restrict__ offs, int* __restrict__ cursor,
    const int* __restrict__ partials, int n, int E_) {
  int g = blockIdx.x * blockDim.x + threadIdx.x;
  if (g < n) {
    int v = offs[g] + partials[g >> 10];
    offs[g] = v;
    cursor[g] = v;
  }
  if (g == 0) offs[n] = E_;
}

// 8-way batched fill: 8 independent returning atomics in flight per lane,
// then 8 independent scattered stores (breaks the 1-deep latency chain).
__global__ __launch_bounds__(256) void fill_kernel(const int* __restrict__ ei,
                                                   int* __restrict__ cursor,
                                                   int* __restrict__ csr,
                                                   int E_) {
  const int G = gridDim.x * blockDim.x;
  int g = blockIdx.x * blockDim.x + threadIdx.x;
  for (long long base = g; base < E_; base += (long long)G * 8) {
    int src[8], dst[8], pos[8];
#pragma unroll
    for (int k = 0; k < 8; ++k) {
      long long e = base + (long long)k * G;
      src[k] = (e < E_) ? ei[e] : -1;
      dst[k] = (e < E_) ? ei[E_ + e] : 0;
    }
#pragma unroll
    for (int k = 0; k < 8; ++k)
      if (src[k] >= 0) pos[k] = atomicAdd(&cursor[dst[k]], 1);
#pragma unroll
    for (int k = 0; k < 8; ++k)
      if (src[k] >= 0) csr[pos[k]] = src[k];
  }
}

// ======================= Gather (bf16 rows, fp32 accum) ==================
// One wave per node; lane holds 2 columns packed in one u32.
// 4-deep unroll: 4 index loads -> 4 row loads -> 4 accumulates.
__global__ __launch_bounds__(256) void gather_bf16_kernel(
    const u32* __restrict__ xb, const int* __restrict__ offs,
    const int* __restrict__ csr, u32* __restrict__ hb) {
  int n = blockIdx.x * 4 + (threadIdx.x >> 6);
  int lane = threadIdx.x & 63;
  int beg = offs[n], end = offs[n + 1];
  u32 p = xb[(size_t)n * 64 + lane];
  float a0 = bf16_to_f((u16)(p & 0xffff));
  float a1 = bf16_to_f((u16)(p >> 16));
  float b0 = 0.f, b1 = 0.f;
  int j = beg;
  for (; j + 4 <= end; j += 4) {
    int s0 = csr[j], s1 = csr[j + 1], s2 = csr[j + 2], s3 = csr[j + 3];
    u32 q0 = xb[(size_t)s0 * 64 + lane];
    u32 q1 = xb[(size_t)s1 * 64 + lane];
    u32 q2 = xb[(size_t)s2 * 64 + lane];
    u32 q3 = xb[(size_t)s3 * 64 + lane];
    a0 += bf16_to_f((u16)(q0 & 0xffff));
    a1 += bf16_to_f((u16)(q0 >> 16));
    b0 += bf16_to_f((u16)(q1 & 0xffff));
    b1 += bf16_to_f((u16)(q1 >> 16));
    a0 += bf16_to_f((u16)(q2 & 0xffff));
    a1 += bf16_to_f((u16)(q2 >> 16));
    b0 += bf16_to_f((u16)(q3 & 0xffff));
    b1 += bf16_to_f((u16)(q3 >> 16));
  }
  for (; j < end; ++j) {
    u32 q = xb[(size_t)csr[j] * 64 + lane];
    a0 += bf16_to_f((u16)(q & 0xffff));
    a1 += bf16_to_f((u16)(q >> 16));
  }
  a0 += b0;
  a1 += b1;
  hb[(size_t)n * 64 + lane] = ((u32)f_to_bf16(a1) << 16) | (u32)f_to_bf16(a0);
}

// ======================= MFMA MLP =======================
__global__ __launch_bounds__(256) void mlp_mfma_kernel(
    const u16* __restrict__ hb, const u16* __restrict__ Wt1,
    const u16* __restrict__ Wt2, const float* __restrict__ b1,
    const float* __restrict__ b2, float* __restrict__ out) {
  __shared__ u16 sH1[4][16 * DIM];  // 16 KB total, per-wave slab
  const int tid = threadIdx.x;
  const int wv = tid >> 6;
  const int lane = tid & 63;
  const int lr = lane & 15;
  const int lq = lane >> 4;
  const int row0 = blockIdx.x * 64 + wv * 16;

  // ---- layer 1 ----
  bf16x8 a[4];
  {
    int r = row0 + lr;
    if (r > N_NODES - 1) r = N_NODES - 1;
#pragma unroll
    for (int ks = 0; ks < 4; ++ks)
      a[ks] = *reinterpret_cast<const bf16x8*>(hb + (size_t)r * DIM + ks * 32 +
                                               lq * 8);
  }
  f32x4 acc[8];
#pragma unroll
  for (int ct = 0; ct < 8; ++ct) {
    f32x4 c = {0.f, 0.f, 0.f, 0.f};
#pragma unroll
    for (int ks = 0; ks < 4; ++ks) {
      bf16x8 b = *reinterpret_cast<const bf16x8*>(
          Wt1 + (ct * 16 + lr) * DIM + ks * 32 + lq * 8);
      c = __builtin_amdgcn_mfma_f32_16x16x32_bf16(a[ks], b, c, 0, 0, 0);
    }
    acc[ct] = c;
  }
  char* slab = reinterpret_cast<char*>(&sH1[wv][0]);
#pragma unroll
  for (int ct = 0; ct < 8; ++ct) {
    int c = ct * 16 + lr;
    float bias = b1[c];
#pragma unroll
    for (int j = 0; j < 4; ++j) {
      int rl = lq * 4 + j;
      float y = fmaxf(acc[ct][j] + bias, 0.f);
      int byte = rl * 256 + ((c * 2) ^ ((rl & 7) << 4));
      *reinterpret_cast<u16*>(slab + byte) = f_to_bf16(y);
    }
  }
  __syncthreads();

  // ---- layer 2 ----
  bf16x8 a2[4];
#pragma unroll
  for (int ks = 0; ks < 4; ++ks) {
    int byte = lr * 256 + (((ks * 32 + lq * 8) * 2) ^ ((lr & 7) << 4));
    a2[ks] = *reinterpret_cast<const bf16x8*>(slab + byte);
  }
#pragma unroll
  for (int ct = 0; ct < 8; ++ct) {
    f32x4 c = {0.f, 0.f, 0.f, 0.f};
#pragma unroll
    for (int ks = 0; ks < 4; ++ks) {
      bf16x8 b = *reinterpret_cast<const bf16x8*>(
          Wt2 + (ct * 16 + lr) * DIM + ks * 32 + lq * 8);
      c = __builtin_amdgcn_mfma_f32_16x16x32_bf16(a2[ks], b, c, 0, 0, 0);
    }
    acc[ct] = c;
  }
#pragma unroll
  for (int ct = 0; ct < 8; ++ct) {
    int c = ct * 16 + lr;
    float bias = b2[c];
#pragma unroll
    for (int j = 0; j < 4; ++j) {
      int r = row0 + lq * 4 + j;
      if (r < N_NODES)
        out[(size_t)r * DIM + c] = fmaxf(acc[ct][j] + bias, 0.f);
    }
  }
}

// ======================= BatchNorm =======================
__global__ __launch_bounds__(256) void bn_stats_kernel(
    const float* __restrict__ h, float* __restrict__ stats) {
  int col = threadIdx.x & 127;
  int rsub = threadIdx.x >> 7;
  int rstep = gridDim.x * 2;
  float s = 0.f, ss = 0.f;
  for (int r = blockIdx.x * 2 + rsub; r < N_NODES; r += rstep) {
    float v = h[(size_t)r * DIM + col];
    s += v;
    ss += v * v;
  }
  __shared__ float ls[256], lss[256];
  ls[threadIdx.x] = s;
  lss[threadIdx.x] = ss;
  __syncthreads();
  if (threadIdx.x < 128) {
    atomicAdd(&stats[col], ls[threadIdx.x] + ls[threadIdx.x + 128]);
    atomicAdd(&stats[DIM + col], lss[threadIdx.x] + lss[threadIdx.x + 128]);
  }
}

__global__ void bn_scale_kernel(const float* __restrict__ stats,
                                const float* __restrict__ gamma,
                                const float* __restrict__ beta,
                                float* __restrict__ sc) {
  int c = threadIdx.x;  // 128
  float mean = stats[c] / (float)N_NODES;
  float var = stats[DIM + c] / (float)N_NODES - mean * mean;
  float scale = gamma[c] * rsqrtf(var + 1e-5f);
  sc[c] = scale;
  sc[DIM + c] = beta[c] - mean * scale;
}

__global__ __launch_bounds__(256) void bn_apply_kernel(
    float* __restrict__ h, const float* __restrict__ sc) {
  size_t total = (size_t)N_NODES * DIM / 4;
  size_t stride = (size_t)gridDim.x * blockDim.x;
  for (size_t i = (size_t)blockIdx.x * blockDim.x + threadIdx.x; i < total;
       i += stride) {
    float4 v = reinterpret_cast<float4*>(h)[i];
    int c = (int)((i * 4) & 127);
    v.x = v.x * sc[c + 0] + sc[DIM + c + 0];
    v.y = v.y * sc[c + 1] + sc[DIM + c + 1];
    v.z = v.z * sc[c + 2] + sc[DIM + c + 2];
    v.w = v.w * sc[c + 3] + sc[DIM + c + 3];
    reinterpret_cast<float4*>(h)[i] = v;
  }
}

// ======================= Fallback kernels (f32 paths) =======================
__global__ __launch_bounds__(128) void gather_f32_kernel(
    const float* __restrict__ x, const int* __restrict__ offs,
    const int* __restrict__ csr, float* __restrict__ h) {
  int n = blockIdx.x;
  int c = threadIdx.x;
  int beg = offs[n], end = offs[n + 1];
  float acc = x[(size_t)n * DIM + c];
  for (int j = beg; j < end; ++j) acc += x[(size_t)csr[j] * DIM + c];
  h[(size_t)n * DIM + c] = acc;
}

__global__ __launch_bounds__(256) void scatter_kernel(
    const float* __restrict__ x, const int* __restrict__ ei,
    float* __restrict__ h, int E_) {
  long long total = (long long)E_ * 32;
  long long stride = (long long)gridDim.x * blockDim.x;
  for (long long idx = (long long)blockIdx.x * blockDim.x + threadIdx.x;
       idx < total; idx += stride) {
    int e = (int)(idx >> 5);
    int q = (int)(idx & 31);
    float4 v =
        *reinterpret_cast<const float4*>(x + (size_t)ei[e] * DIM + q * 4);
    float* p = h + (size_t)ei[E_ + e] * DIM + q * 4;
    atomicAdd(p + 0, v.x);
    atomicAdd(p + 1, v.y);
    atomicAdd(p + 2, v.z);
    atomicAdd(p + 3, v.w);
  }
}

__global__ __launch_bounds__(256) void add_x_kernel(const float* __restrict__ x,
                                                    float* __restrict__ h) {
  size_t total = (size_t)N_NODES * DIM / 4;
  size_t stride = (size_t)gridDim.x * blockDim.x;
  for (size_t i = (size_t)blockIdx.x * blockDim.x + threadIdx.x; i < total;
       i += stride) {
    float4 v = reinterpret_cast<float4*>(h)[i];
    float4 xv = reinterpret_cast<const float4*>(x)[i];
    v.x += xv.x; v.y += xv.y; v.z += xv.z; v.w += xv.w;
    reinterpret_cast<float4*>(h)[i] = v;
  }
}

__global__ __launch_bounds__(256) void mlp_valu_kernel(
    float* hbuf, const float* __restrict__ W1, const float* __restrict__ b1,
    const float* __restrict__ W2, const float* __restrict__ b2) {
  __shared__ float sW[DIM * DIM];
  __shared__ float sH[32][DIM];
  const int tid = threadIdx.x;
  const int col = tid & 127;
  const int rhalf = tid >> 7;
  const int row0 = blockIdx.x * 32;

  for (int i = tid; i < DIM * DIM; i += 256) sW[i] = W1[i];
  for (int i = tid; i < 32 * DIM; i += 256) {
    int r = i >> 7, c = i & 127;
    sH[r][c] = hbuf[(size_t)(row0 + r) * DIM + c];
  }
  __syncthreads();
  float acc[16];
  float bias = b1[col];
#pragma unroll
  for (int j = 0; j < 16; ++j) acc[j] = bias;
#pragma unroll 4
  for (int k = 0; k < DIM; ++k) {
    float w = sW[k * DIM + col];
#pragma unroll
    for (int j = 0; j < 16; ++j) acc[j] = fmaf(sH[2 * j + rhalf][k], w, acc[j]);
  }
  __syncthreads();
  for (int i = tid; i < DIM * DIM; i += 256) sW[i] = W2[i];
#pragma unroll
  for (int j = 0; j < 16; ++j) sH[2 * j + rhalf][col] = fmaxf(acc[j], 0.f);
  __syncthreads();
  float bias2 = b2[col];
#pragma unroll
  for (int j = 0; j < 16; ++j) acc[j] = bias2;
#pragma unroll 4
  for (int k = 0; k < DIM; ++k) {
    float w = sW[k * DIM + col];
#pragma unroll
    for (int j = 0; j < 16; ++j) acc[j] = fmaf(sH[2 * j + rhalf][k], w, acc[j]);
  }
#pragma unroll
  for (int j = 0; j < 16; ++j)
    hbuf[(size_t)(row0 + 2 * j + rhalf) * DIM + col] = fmaxf(acc[j], 0.f);
}

extern "C" void kernel_launch(void* const* d_in, const int* in_sizes, int n_in,
                              void* d_out, int out_size, void* d_ws,
                              size_t ws_size, hipStream_t stream) {
  const float* x = (const float*)d_in[0];
  const int* ei = (const int*)d_in[1];
  const float* W1 = (const float*)d_in[3];
  const float* b1 = (const float*)d_in[4];
  const float* W2 = (const float*)d_in[5];
  const float* b2 = (const float*)d_in[6];
  const float* gamma = (const float*)d_in[7];
  const float* beta = (const float*)d_in[8];
  float* out = (float*)d_out;
  int E_ = in_sizes[1] / 2;

  // ---- full-path workspace layout (all 16B-aligned) ----
  const size_t XB_B = (size_t)N_NODES * DIM * 2;  // 25.6e6
  char* w = (char*)d_ws;
  u16* xb = (u16*)w;
  u16* hb = (u16*)(w + XB_B);
  u16* Wt1 = (u16*)(w + 2 * XB_B);
  u16* Wt2 = (u16*)(w + 2 * XB_B + 32768);
  int* offs = (int*)(w + 2 * XB_B + 65536);
  int* cursor = offs + N_NODES + 1;
  int* partials = cursor + N_NODES;
  int* csr = partials + 128;
  float* stats = (float*)(csr + E_);
  size_t need_full =
      2 * XB_B + 65536 + ((size_t)2 * N_NODES + 129 + E_) * 4 + 3072;

  // ---- CSR-only fallback layout ----
  int* f_offs = (int*)d_ws;
  int* f_cursor = f_offs + N_NODES + 1;
  int* f_partials = f_cursor + N_NODES;
  int* f_csr = f_partials + 128;
  float* f_stats = (float*)(f_csr + E_);
  size_t need_csr = ((size_t)2 * N_NODES + 129 + E_) * 4 + 3072;

  const int nScanBlocks = (N_NODES + 1023) / 1024;  // 98
  const int nEdgeBlocks = (E_ + 2047) / 2048;       // 8 edges/thread

  if (ws_size >= need_full) {
    cvt_x_kernel<<<2048, 256, 0, stream>>>(x, xb);
    cvt_w_kernel<<<64, 256, 0, stream>>>(W1, Wt1);
    cvt_w_kernel<<<64, 256, 0, stream>>>(W2, Wt2);
    hipMemsetAsync(cursor, 0, (size_t)N_NODES * sizeof(int), stream);
    hipMemsetAsync(stats, 0, 768 * sizeof(float), stream);
    hist_kernel<<<nEdgeBlocks, 256, 0, stream>>>(ei, cursor, E_);
    scan_block_kernel<<<nScanBlocks, 256, 0, stream>>>(cursor, offs, partials,
                                                       N_NODES);
    scan_partials_kernel<<<1, 128, 0, stream>>>(partials, nScanBlocks);
    scan_add_kernel<<<(N_NODES + 255) / 256, 256, 0, stream>>>(
        offs, cursor, partials, N_NODES, E_);
    fill_kernel<<<nEdgeBlocks, 256, 0, stream>>>(ei, cursor, csr, E_);
    gather_bf16_kernel<<<N_NODES / 4, 256, 0, stream>>>((const u32*)xb, offs,
                                                        csr, (u32*)hb);
    mlp_mfma_kernel<<<(N_NODES + 63) / 64, 256, 0, stream>>>(hb, Wt1, Wt2, b1,
                                                             b2, out);
    bn_stats_kernel<<<1024, 256, 0, stream>>>(out, stats);
    bn_scale_kernel<<<1, 128, 0, stream>>>(stats, gamma, beta, stats + 256);
    bn_apply_kernel<<<2048, 256, 0, stream>>>(out, stats + 256);
  } else if (ws_size >= need_csr) {
    hipMemsetAsync(f_cursor, 0, (size_t)N_NODES * sizeof(int), stream);
    hipMemsetAsync(f_stats, 0, 768 * sizeof(float), stream);
    hist_kernel<<<nEdgeBlocks, 256, 0, stream>>>(ei, f_cursor, E_);
    scan_block_kernel<<<nScanBlocks, 256, 0, stream>>>(f_cursor, f_offs,
                                                       f_partials, N_NODES);
    scan_partials_kernel<<<1, 128, 0, stream>>>(f_partials, nScanBlocks);
    scan_add_kernel<<<(N_NODES + 255) / 256, 256, 0, stream>>>(
        f_offs, f_cursor, f_partials, N_NODES, E_);
    fill_kernel<<<nEdgeBlocks, 256, 0, stream>>>(ei, f_cursor, f_csr, E_);
    gather_f32_kernel<<<N_NODES, 128, 0, stream>>>(x, f_offs, f_csr, out);
    mlp_valu_kernel<<<(N_NODES + 31) / 32, 256, 0, stream>>>(out, W1, b1, W2,
                                                             b2);
    bn_stats_kernel<<<1024, 256, 0, stream>>>(out, f_stats);
    bn_scale_kernel<<<1, 128, 0, stream>>>(f_stats, gamma, beta, f_stats + 256);
    bn_apply_kernel<<<2048, 256, 0, stream>>>(out, f_stats + 256);
  } else {
    float* s2 = (float*)d_ws;
    hipMemsetAsync(out, 0, (size_t)N_NODES * DIM * sizeof(float), stream);
    hipMemsetAsync(s2, 0, 768 * sizeof(float), stream);
    scatter_kernel<<<4096, 256, 0, stream>>>(x, ei, out, E_);
    add_x_kernel<<<2048, 256, 0, stream>>>(x, out);
    mlp_valu_kernel<<<(N_NODES + 31) / 32, 256, 0, stream>>>(out, W1, b1, W2,
                                                             b2);
    bn_stats_kernel<<<1024, 256, 0, stream>>>(out, s2);
    bn_scale_kernel<<<1, 128, 0, stream>>>(s2, gamma, beta, s2 + 256);
    bn_apply_kernel<<<2048, 256, 0, stream>>>(out, s2 + 256);
  }
}

// Round 6
// 448.477 us; speedup vs baseline: 12.5669x; 1.4865x over previous
//
#include <hip/hip_runtime.h>

#define N_NODES 100000
#define DIM 128
#define NBUCK 391  // ceil(N/256), bucket = dst>>8 (256 nodes per bucket)
#define RING 32    // ring slots per bucket in partition LDS (2 chunks of 16)
#define CAP 12288  // max edges per bucket in bsort (mean 8187, +45 sigma)

typedef unsigned int u32;
typedef unsigned short u16;
typedef __attribute__((ext_vector_type(8))) short bf16x8;
typedef __attribute__((ext_vector_type(4))) float f32x4;

__device__ __forceinline__ float bf16_to_f(u16 v) {
  return __uint_as_float(((u32)v) << 16);
}
__device__ __forceinline__ u16 f_to_bf16(float f) {
  u32 b = __float_as_uint(f);
  b += 0x7fff + ((b >> 16) & 1);  // round-to-nearest-even
  return (u16)(b >> 16);
}

// ======================= prep: conversions =======================
__global__ __launch_bounds__(256) void cvt_x_kernel(const float* __restrict__ x,
                                                    u16* __restrict__ xb) {
  int total = N_NODES * DIM / 4;
  int stride = gridDim.x * blockDim.x;
  for (int i = blockIdx.x * blockDim.x + threadIdx.x; i < total; i += stride) {
    float4 v = reinterpret_cast<const float4*>(x)[i];
    ushort4 o;
    o.x = f_to_bf16(v.x);
    o.y = f_to_bf16(v.y);
    o.z = f_to_bf16(v.z);
    o.w = f_to_bf16(v.w);
    reinterpret_cast<ushort4*>(xb)[i] = o;
  }
}

// Wt[c][k] = bf16(W[k][c]) : B^T image, k-contiguous for MFMA B-fragments.
__global__ void cvt_w_kernel(const float* __restrict__ W, u16* __restrict__ Wt) {
  int id = blockIdx.x * 256 + threadIdx.x;  // id = c*128 + k
  int c = id >> 7, k = id & 127;
  Wt[id] = f_to_bf16(W[k * DIM + c]);
}

// ======================= bucketed CSR build =======================
// Bucket histogram: LDS-aggregated (391 global atomics per block).
__global__ __launch_bounds__(256) void bhist_kernel(const int* __restrict__ ei,
                                                    int* __restrict__ bcnt,
                                                    int E_) {
  __shared__ int lc[NBUCK];
  for (int i = threadIdx.x; i < NBUCK; i += 256) lc[i] = 0;
  __syncthreads();
  int G = gridDim.x * blockDim.x;
  for (int e = blockIdx.x * blockDim.x + threadIdx.x; e < E_; e += G)
    atomicAdd(&lc[((u32)ei[E_ + e]) >> 8], 1);
  __syncthreads();
  for (int i = threadIdx.x; i < NBUCK; i += 256)
    if (lc[i]) atomicAdd(&bcnt[i], lc[i]);
}

// Exclusive scan over NBUCK counts (one block, 2 elems/thread).
__global__ void bscan_kernel(const int* __restrict__ bcnt,
                             int* __restrict__ boffs, int* __restrict__ gcur) {
  __shared__ int s[256];
  int t = threadIdx.x;
  int v0 = (2 * t < NBUCK) ? bcnt[2 * t] : 0;
  int v1 = (2 * t + 1 < NBUCK) ? bcnt[2 * t + 1] : 0;
  int ts = v0 + v1;
  s[t] = ts;
  __syncthreads();
  for (int o = 1; o < 256; o <<= 1) {
    int u = (t >= o) ? s[t - o] : 0;
    __syncthreads();
    s[t] += u;
    __syncthreads();
  }
  int excl = s[t] - ts;
  if (2 * t <= NBUCK) boffs[2 * t] = excl;
  if (2 * t + 1 <= NBUCK) boffs[2 * t + 1] = excl + v0;
  if (2 * t < NBUCK) gcur[2 * t] = excl;
  if (2 * t + 1 < NBUCK) gcur[2 * t + 1] = excl + v0;
}

// Partition edges into buckets. All fine-grained scatter is in LDS; global
// writes are 64B chunk flushes (16 lanes cooperative) + tiny residuals.
__global__ __launch_bounds__(256) void partition_kernel(
    const int* __restrict__ ei, int* __restrict__ gcur,
    u32* __restrict__ packed, int E_) {
  __shared__ u32 ring[NBUCK * RING];  // 50 KB
  __shared__ int lcur[NBUCK];
  __shared__ int fq[256];
  __shared__ int fqn;
  const int t = threadIdx.x;
  for (int i = t; i < NBUCK; i += 256) lcur[i] = 0;
  if (t == 0) fqn = 0;
  __syncthreads();

  int perBlk = (E_ + gridDim.x - 1) / gridDim.x;
  int s0 = blockIdx.x * perBlk;
  int s1 = min(s0 + perBlk, E_);
  const int grp = t >> 4, ln = t & 15;

  for (int tile = s0; tile < s1; tile += 2048) {
    int tEnd = min(tile + 2048, s1);
    for (int e = tile + t; e < tEnd; e += 256) {
      int src = ei[e];
      u32 dst = (u32)ei[E_ + e];
      int b = dst >> 8;
      u32 pk = (u32)src | ((dst & 255u) << 17);
      int idx = atomicAdd(&lcur[b], 1);
      ring[b * RING + (idx & (RING - 1))] = pk;
      if ((idx & 15) == 15) {  // 16th claimant queues this chunk
        int qi = atomicAdd(&fqn, 1);
        fq[qi] = (b << 1) | ((idx >> 4) & 1);
      }
    }
    __syncthreads();
    int nq = fqn;
    for (int q = grp; q < nq; q += 16) {  // 16 groups x 16 lanes
      int ent = fq[q];
      int b = ent >> 1, half = ent & 1;
      int pos;
      if (ln == 0) pos = atomicAdd(&gcur[b], 16);
      pos = __shfl(pos, 0, 16);
      packed[pos + ln] = ring[b * RING + half * 16 + ln];  // 64B coalesced
    }
    __syncthreads();
    if (t == 0) fqn = 0;
    __syncthreads();
  }
  // residual (partial chunk) flush
  for (int b = t; b < NBUCK; b += 256) {
    int c = lcur[b];
    int r = c & 15;
    if (r) {
      int pos = atomicAdd(&gcur[b], r);
      int half = (c >> 4) & 1;
      for (int i = 0; i < r; ++i) packed[pos + i] = ring[b * RING + half * 16 + i];
    }
  }
}

// Per-bucket counting sort in LDS -> exact CSR (in place on `packed`) +
// per-node offsets. Global reads/writes fully coalesced.
__global__ __launch_bounds__(256) void bsort_kernel(u32* __restrict__ packed,
                                                    const int* __restrict__ boffs,
                                                    int* __restrict__ offs,
                                                    int E_) {
  __shared__ u32 sorted_[CAP];  // 48 KB
  __shared__ int hist[256], cur[256], ss[256];
  const int b = blockIdx.x, t = threadIdx.x;
  int base = boffs[b];
  int cnt = boffs[b + 1] - base;
  if (cnt > CAP) cnt = CAP;  // statistically unreachable guard
  hist[t] = 0;
  __syncthreads();
  for (int i = t; i < cnt; i += 256) atomicAdd(&hist[packed[base + i] >> 17], 1);
  __syncthreads();
  int hv = hist[t];
  ss[t] = hv;
  __syncthreads();
  for (int o = 1; o < 256; o <<= 1) {
    int u = (t >= o) ? ss[t - o] : 0;
    __syncthreads();
    ss[t] += u;
    __syncthreads();
  }
  int excl = ss[t] - hv;
  cur[t] = excl;
  __syncthreads();
  for (int i = t; i < cnt; i += 256) {
    u32 v = packed[base + i];
    int p = atomicAdd(&cur[v >> 17], 1);
    sorted_[p] = v & 0x1FFFFu;
  }
  __syncthreads();
  for (int i = t; i < cnt; i += 256) packed[base + i] = sorted_[i];
  int node = b * 256 + t;
  if (node < N_NODES) offs[node] = base + excl;
  if (b == 0 && t == 0) offs[N_NODES] = E_;
}

// ======================= Gather (bf16 rows, fp32 accum) ==================
// One wave per node; lane holds 2 columns packed in one u32. 8-deep ILP.
__global__ __launch_bounds__(256) void gather_bf16_kernel(
    const u32* __restrict__ xb, const int* __restrict__ offs,
    const int* __restrict__ csr, u32* __restrict__ hb) {
  int n = blockIdx.x * 4 + (threadIdx.x >> 6);
  int lane = threadIdx.x & 63;
  int beg = offs[n], end = offs[n + 1];
  u32 p = xb[(size_t)n * 64 + lane];
  float a0 = bf16_to_f((u16)(p & 0xffff));
  float a1 = bf16_to_f((u16)(p >> 16));
  float b0 = 0.f, b1 = 0.f, c0 = 0.f, c1 = 0.f, d0 = 0.f, d1 = 0.f;
  int j = beg;
  for (; j + 8 <= end; j += 8) {
    int s0 = csr[j], s1 = csr[j + 1], s2 = csr[j + 2], s3 = csr[j + 3];
    int s4 = csr[j + 4], s5 = csr[j + 5], s6 = csr[j + 6], s7 = csr[j + 7];
    u32 q0 = xb[(size_t)s0 * 64 + lane];
    u32 q1 = xb[(size_t)s1 * 64 + lane];
    u32 q2 = xb[(size_t)s2 * 64 + lane];
    u32 q3 = xb[(size_t)s3 * 64 + lane];
    u32 q4 = xb[(size_t)s4 * 64 + lane];
    u32 q5 = xb[(size_t)s5 * 64 + lane];
    u32 q6 = xb[(size_t)s6 * 64 + lane];
    u32 q7 = xb[(size_t)s7 * 64 + lane];
    a0 += bf16_to_f((u16)(q0 & 0xffff));
    a1 += bf16_to_f((u16)(q0 >> 16));
    b0 += bf16_to_f((u16)(q1 & 0xffff));
    b1 += bf16_to_f((u16)(q1 >> 16));
    c0 += bf16_to_f((u16)(q2 & 0xffff));
    c1 += bf16_to_f((u16)(q2 >> 16));
    d0 += bf16_to_f((u16)(q3 & 0xffff));
    d1 += bf16_to_f((u16)(q3 >> 16));
    a0 += bf16_to_f((u16)(q4 & 0xffff));
    a1 += bf16_to_f((u16)(q4 >> 16));
    b0 += bf16_to_f((u16)(q5 & 0xffff));
    b1 += bf16_to_f((u16)(q5 >> 16));
    c0 += bf16_to_f((u16)(q6 & 0xffff));
    c1 += bf16_to_f((u16)(q6 >> 16));
    d0 += bf16_to_f((u16)(q7 & 0xffff));
    d1 += bf16_to_f((u16)(q7 >> 16));
  }
  for (; j < end; ++j) {
    u32 q = xb[(size_t)csr[j] * 64 + lane];
    a0 += bf16_to_f((u16)(q & 0xffff));
    a1 += bf16_to_f((u16)(q >> 16));
  }
  a0 += b0 + c0 + d0;
  a1 += b1 + c1 + d1;
  hb[(size_t)n * 64 + lane] = ((u32)f_to_bf16(a1) << 16) | (u32)f_to_bf16(a0);
}

// ======================= MFMA MLP =======================
__global__ __launch_bounds__(256) void mlp_mfma_kernel(
    const u16* __restrict__ hb, const u16* __restrict__ Wt1,
    const u16* __restrict__ Wt2, const float* __restrict__ b1,
    const float* __restrict__ b2, float* __restrict__ out) {
  __shared__ u16 sH1[4][16 * DIM];  // 16 KB total, per-wave slab
  const int tid = threadIdx.x;
  const int wv = tid >> 6;
  const int lane = tid & 63;
  const int lr = lane & 15;
  const int lq = lane >> 4;
  const int row0 = blockIdx.x * 64 + wv * 16;

  // ---- layer 1 ----
  bf16x8 a[4];
  {
    int r = row0 + lr;
    if (r > N_NODES - 1) r = N_NODES - 1;
#pragma unroll
    for (int ks = 0; ks < 4; ++ks)
      a[ks] = *reinterpret_cast<const bf16x8*>(hb + (size_t)r * DIM + ks * 32 +
                                               lq * 8);
  }
  f32x4 acc[8];
#pragma unroll
  for (int ct = 0; ct < 8; ++ct) {
    f32x4 c = {0.f, 0.f, 0.f, 0.f};
#pragma unroll
    for (int ks = 0; ks < 4; ++ks) {
      bf16x8 b = *reinterpret_cast<const bf16x8*>(
          Wt1 + (ct * 16 + lr) * DIM + ks * 32 + lq * 8);
      c = __builtin_amdgcn_mfma_f32_16x16x32_bf16(a[ks], b, c, 0, 0, 0);
    }
    acc[ct] = c;
  }
  char* slab = reinterpret_cast<char*>(&sH1[wv][0]);
#pragma unroll
  for (int ct = 0; ct < 8; ++ct) {
    int c = ct * 16 + lr;
    float bias = b1[c];
#pragma unroll
    for (int j = 0; j < 4; ++j) {
      int rl = lq * 4 + j;
      float y = fmaxf(acc[ct][j] + bias, 0.f);
      int byte = rl * 256 + ((c * 2) ^ ((rl & 7) << 4));
      *reinterpret_cast<u16*>(slab + byte) = f_to_bf16(y);
    }
  }
  __syncthreads();

  // ---- layer 2 ----
  bf16x8 a2[4];
#pragma unroll
  for (int ks = 0; ks < 4; ++ks) {
    int byte = lr * 256 + (((ks * 32 + lq * 8) * 2) ^ ((lr & 7) << 4));
    a2[ks] = *reinterpret_cast<const bf16x8*>(slab + byte);
  }
#pragma unroll
  for (int ct = 0; ct < 8; ++ct) {
    f32x4 c = {0.f, 0.f, 0.f, 0.f};
#pragma unroll
    for (int ks = 0; ks < 4; ++ks) {
      bf16x8 b = *reinterpret_cast<const bf16x8*>(
          Wt2 + (ct * 16 + lr) * DIM + ks * 32 + lq * 8);
      c = __builtin_amdgcn_mfma_f32_16x16x32_bf16(a2[ks], b, c, 0, 0, 0);
    }
    acc[ct] = c;
  }
#pragma unroll
  for (int ct = 0; ct < 8; ++ct) {
    int c = ct * 16 + lr;
    float bias = b2[c];
#pragma unroll
    for (int j = 0; j < 4; ++j) {
      int r = row0 + lq * 4 + j;
      if (r < N_NODES)
        out[(size_t)r * DIM + c] = fmaxf(acc[ct][j] + bias, 0.f);
    }
  }
}

// ======================= BatchNorm =======================
__global__ __launch_bounds__(256) void bn_stats_kernel(
    const float* __restrict__ h, float* __restrict__ stats) {
  int col = threadIdx.x & 127;
  int rsub = threadIdx.x >> 7;
  int rstep = gridDim.x * 2;
  float s = 0.f, ss = 0.f;
  for (int r = blockIdx.x * 2 + rsub; r < N_NODES; r += rstep) {
    float v = h[(size_t)r * DIM + col];
    s += v;
    ss += v * v;
  }
  __shared__ float ls[256], lss[256];
  ls[threadIdx.x] = s;
  lss[threadIdx.x] = ss;
  __syncthreads();
  if (threadIdx.x < 128) {
    atomicAdd(&stats[col], ls[threadIdx.x] + ls[threadIdx.x + 128]);
    atomicAdd(&stats[DIM + col], lss[threadIdx.x] + lss[threadIdx.x + 128]);
  }
}

__global__ void bn_scale_kernel(const float* __restrict__ stats,
                                const float* __restrict__ gamma,
                                const float* __restrict__ beta,
                                float* __restrict__ sc) {
  int c = threadIdx.x;  // 128
  float mean = stats[c] / (float)N_NODES;
  float var = stats[DIM + c] / (float)N_NODES - mean * mean;
  float scale = gamma[c] * rsqrtf(var + 1e-5f);
  sc[c] = scale;
  sc[DIM + c] = beta[c] - mean * scale;
}

__global__ __launch_bounds__(256) void bn_apply_kernel(
    float* __restrict__ h, const float* __restrict__ sc) {
  size_t total = (size_t)N_NODES * DIM / 4;
  size_t stride = (size_t)gridDim.x * blockDim.x;
  for (size_t i = (size_t)blockIdx.x * blockDim.x + threadIdx.x; i < total;
       i += stride) {
    float4 v = reinterpret_cast<float4*>(h)[i];
    int c = (int)((i * 4) & 127);
    v.x = v.x * sc[c + 0] + sc[DIM + c + 0];
    v.y = v.y * sc[c + 1] + sc[DIM + c + 1];
    v.z = v.z * sc[c + 2] + sc[DIM + c + 2];
    v.w = v.w * sc[c + 3] + sc[DIM + c + 3];
    reinterpret_cast<float4*>(h)[i] = v;
  }
}

// ======================= Fallback kernels =======================
__global__ __launch_bounds__(256) void hist_kernel(const int* __restrict__ ei,
                                                   int* __restrict__ deg,
                                                   int E_) {
  int stride = gridDim.x * blockDim.x;
  for (int e = blockIdx.x * blockDim.x + threadIdx.x; e < E_; e += stride)
    atomicAdd(&deg[ei[E_ + e]], 1);
}

__global__ __launch_bounds__(256) void scan_block_kernel(
    const int* __restrict__ deg, int* __restrict__ offs,
    int* __restrict__ partials, int n) {
  const int tid = threadIdx.x;
  int g = blockIdx.x * 1024 + tid * 4;
  int v0 = (g + 0 < n) ? deg[g + 0] : 0;
  int v1 = (g + 1 < n) ? deg[g + 1] : 0;
  int v2 = (g + 2 < n) ? deg[g + 2] : 0;
  int v3 = (g + 3 < n) ? deg[g + 3] : 0;
  int tsum = v0 + v1 + v2 + v3;
  __shared__ int s[256];
  s[tid] = tsum;
  __syncthreads();
  for (int off = 1; off < 256; off <<= 1) {
    int t = (tid >= off) ? s[tid - off] : 0;
    __syncthreads();
    s[tid] += t;
    __syncthreads();
  }
  int excl = s[tid] - tsum;
  if (g + 0 < n) offs[g + 0] = excl;
  if (g + 1 < n) offs[g + 1] = excl + v0;
  if (g + 2 < n) offs[g + 2] = excl + v0 + v1;
  if (g + 3 < n) offs[g + 3] = excl + v0 + v1 + v2;
  if (tid == 255) partials[blockIdx.x] = s[255];
}

__global__ void scan_partials_kernel(int* __restrict__ partials, int nb) {
  const int tid = threadIdx.x;
  int v = (tid < nb) ? partials[tid] : 0;
  __shared__ int s[128];
  s[tid] = v;
  __syncthreads();
  for (int off = 1; off < 128; off <<= 1) {
    int t = (tid >= off) ? s[tid - off] : 0;
    __syncthreads();
    s[tid] += t;
    __syncthreads();
  }
  if (tid < nb) partials[tid] = s[tid] - v;
}

__global__ __launch_bounds__(256) void scan_add_kernel(
    int* __restrict__ offs, int* __restrict__ cursor,
    const int* __restrict__ partials, int n, int E_) {
  int g = blockIdx.x * blockDim.x + threadIdx.x;
  if (g < n) {
    int v = offs[g] + partials[g >> 10];
    offs[g] = v;
    cursor[g] = v;
  }
  if (g == 0) offs[n] = E_;
}

__global__ __launch_bounds__(256) void fill_kernel(const int* __restrict__ ei,
                                                   int* __restrict__ cursor,
                                                   int* __restrict__ csr,
                                                   int E_) {
  const int G = gridDim.x * blockDim.x;
  int g = blockIdx.x * blockDim.x + threadIdx.x;
  for (long long base = g; base < E_; base += (long long)G * 8) {
    int src[8], dst[8], pos[8];
#pragma unroll
    for (int k = 0; k < 8; ++k) {
      long long e = base + (long long)k * G;
      src[k] = (e < E_) ? ei[e] : -1;
      dst[k] = (e < E_) ? ei[E_ + e] : 0;
    }
#pragma unroll
    for (int k = 0; k < 8; ++k)
      if (src[k] >= 0) pos[k] = atomicAdd(&cursor[dst[k]], 1);
#pragma unroll
    for (int k = 0; k < 8; ++k)
      if (src[k] >= 0) csr[pos[k]] = src[k];
  }
}

__global__ __launch_bounds__(128) void gather_f32_kernel(
    const float* __restrict__ x, const int* __restrict__ offs,
    const int* __restrict__ csr, float* __restrict__ h) {
  int n = blockIdx.x;
  int c = threadIdx.x;
  int beg = offs[n], end = offs[n + 1];
  float acc = x[(size_t)n * DIM + c];
  for (int j = beg; j < end; ++j) acc += x[(size_t)csr[j] * DIM + c];
  h[(size_t)n * DIM + c] = acc;
}

__global__ __launch_bounds__(256) void scatter_kernel(
    const float* __restrict__ x, const int* __restrict__ ei,
    float* __restrict__ h, int E_) {
  long long total = (long long)E_ * 32;
  long long stride = (long long)gridDim.x * blockDim.x;
  for (long long idx = (long long)blockIdx.x * blockDim.x + threadIdx.x;
       idx < total; idx += stride) {
    int e = (int)(idx >> 5);
    int q = (int)(idx & 31);
    float4 v =
        *reinterpret_cast<const float4*>(x + (size_t)ei[e] * DIM + q * 4);
    float* p = h + (size_t)ei[E_ + e] * DIM + q * 4;
    atomicAdd(p + 0, v.x);
    atomicAdd(p + 1, v.y);
    atomicAdd(p + 2, v.z);
    atomicAdd(p + 3, v.w);
  }
}

__global__ __launch_bounds__(256) void add_x_kernel(const float* __restrict__ x,
                                                    float* __restrict__ h) {
  size_t total = (size_t)N_NODES * DIM / 4;
  size_t stride = (size_t)gridDim.x * blockDim.x;
  for (size_t i = (size_t)blockIdx.x * blockDim.x + threadIdx.x; i < total;
       i += stride) {
    float4 v = reinterpret_cast<float4*>(h)[i];
    float4 xv = reinterpret_cast<const float4*>(x)[i];
    v.x += xv.x; v.y += xv.y; v.z += xv.z; v.w += xv.w;
    reinterpret_cast<float4*>(h)[i] = v;
  }
}

__global__ __launch_bounds__(256) void mlp_valu_kernel(
    float* hbuf, const float* __restrict__ W1, const float* __restrict__ b1,
    const float* __restrict__ W2, const float* __restrict__ b2) {
  __shared__ float sW[DIM * DIM];
  __shared__ float sH[32][DIM];
  const int tid = threadIdx.x;
  const int col = tid & 127;
  const int rhalf = tid >> 7;
  const int row0 = blockIdx.x * 32;

  for (int i = tid; i < DIM * DIM; i += 256) sW[i] = W1[i];
  for (int i = tid; i < 32 * DIM; i += 256) {
    int r = i >> 7, c = i & 127;
    sH[r][c] = hbuf[(size_t)(row0 + r) * DIM + c];
  }
  __syncthreads();
  float acc[16];
  float bias = b1[col];
#pragma unroll
  for (int j = 0; j < 16; ++j) acc[j] = bias;
#pragma unroll 4
  for (int k = 0; k < DIM; ++k) {
    float w = sW[k * DIM + col];
#pragma unroll
    for (int j = 0; j < 16; ++j) acc[j] = fmaf(sH[2 * j + rhalf][k], w, acc[j]);
  }
  __syncthreads();
  for (int i = tid; i < DIM * DIM; i += 256) sW[i] = W2[i];
#pragma unroll
  for (int j = 0; j < 16; ++j) sH[2 * j + rhalf][col] = fmaxf(acc[j], 0.f);
  __syncthreads();
  float bias2 = b2[col];
#pragma unroll
  for (int j = 0; j < 16; ++j) acc[j] = bias2;
#pragma unroll 4
  for (int k = 0; k < DIM; ++k) {
    float w = sW[k * DIM + col];
#pragma unroll
    for (int j = 0; j < 16; ++j) acc[j] = fmaf(sH[2 * j + rhalf][k], w, acc[j]);
  }
#pragma unroll
  for (int j = 0; j < 16; ++j)
    hbuf[(size_t)(row0 + 2 * j + rhalf) * DIM + col] = fmaxf(acc[j], 0.f);
}

extern "C" void kernel_launch(void* const* d_in, const int* in_sizes, int n_in,
                              void* d_out, int out_size, void* d_ws,
                              size_t ws_size, hipStream_t stream) {
  const float* x = (const float*)d_in[0];
  const int* ei = (const int*)d_in[1];
  const float* W1 = (const float*)d_in[3];
  const float* b1 = (const float*)d_in[4];
  const float* W2 = (const float*)d_in[5];
  const float* b2 = (const float*)d_in[6];
  const float* gamma = (const float*)d_in[7];
  const float* beta = (const float*)d_in[8];
  float* out = (float*)d_out;
  int E_ = in_sizes[1] / 2;

  // ---- full-path workspace layout (16B-aligned fields) ----
  const size_t XB_B = (size_t)N_NODES * DIM * 2;  // 25.6e6
  char* w = (char*)d_ws;
  size_t off = 0;
  u16* xb = (u16*)(w + off); off += XB_B;
  u16* hb = (u16*)(w + off); off += XB_B;
  u16* Wt1 = (u16*)(w + off); off += 32768;
  u16* Wt2 = (u16*)(w + off); off += 32768;
  u32* packed = (u32*)(w + off); off += (size_t)E_ * 4;      // doubles as csr
  int* offs = (int*)(w + off); off += ((size_t)N_NODES + 4) * 4;
  int* bcnt = (int*)(w + off); off += 1600;                  // NBUCK ints, padded
  float* stats = (float*)(w + off); off += 3072;             // adjacent to bcnt
  int* boffs = (int*)(w + off); off += 1600;                 // NBUCK+1 ints
  int* gcur = (int*)(w + off); off += 1600;
  size_t need_full = off;

  // ---- CSR-only fallback layout ----
  int* f_offs = (int*)d_ws;
  int* f_cursor = f_offs + N_NODES + 1;
  int* f_partials = f_cursor + N_NODES;
  int* f_csr = f_partials + 128;
  float* f_stats = (float*)(f_csr + E_);
  size_t need_csr = ((size_t)2 * N_NODES + 129 + E_) * 4 + 3072;

  const int nScanBlocks = (N_NODES + 1023) / 1024;  // 98
  const int nEdgeBlocks = (E_ + 2047) / 2048;

  if (ws_size >= need_full) {
    cvt_x_kernel<<<2048, 256, 0, stream>>>(x, xb);
    cvt_w_kernel<<<64, 256, 0, stream>>>(W1, Wt1);
    cvt_w_kernel<<<64, 256, 0, stream>>>(W2, Wt2);
    hipMemsetAsync(bcnt, 0, 1600 + 3072, stream);  // bcnt + stats
    bhist_kernel<<<256, 256, 0, stream>>>(ei, bcnt, E_);
    bscan_kernel<<<1, 256, 0, stream>>>(bcnt, boffs, gcur);
    partition_kernel<<<128, 256, 0, stream>>>(ei, gcur, packed, E_);
    bsort_kernel<<<NBUCK, 256, 0, stream>>>(packed, boffs, offs, E_);
    gather_bf16_kernel<<<N_NODES / 4, 256, 0, stream>>>((const u32*)xb, offs,
                                                        (const int*)packed,
                                                        (u32*)hb);
    mlp_mfma_kernel<<<(N_NODES + 63) / 64, 256, 0, stream>>>(hb, Wt1, Wt2, b1,
                                                             b2, out);
    bn_stats_kernel<<<1024, 256, 0, stream>>>(out, stats);
    bn_scale_kernel<<<1, 128, 0, stream>>>(stats, gamma, beta, stats + 256);
    bn_apply_kernel<<<2048, 256, 0, stream>>>(out, stats + 256);
  } else if (ws_size >= need_csr) {
    hipMemsetAsync(f_cursor, 0, (size_t)N_NODES * sizeof(int), stream);
    hipMemsetAsync(f_stats, 0, 768 * sizeof(float), stream);
    hist_kernel<<<2048, 256, 0, stream>>>(ei, f_cursor, E_);
    scan_block_kernel<<<nScanBlocks, 256, 0, stream>>>(f_cursor, f_offs,
                                                       f_partials, N_NODES);
    scan_partials_kernel<<<1, 128, 0, stream>>>(f_partials, nScanBlocks);
    scan_add_kernel<<<(N_NODES + 255) / 256, 256, 0, stream>>>(
        f_offs, f_cursor, f_partials, N_NODES, E_);
    fill_kernel<<<nEdgeBlocks, 256, 0, stream>>>(ei, f_cursor, f_csr, E_);
    gather_f32_kernel<<<N_NODES, 128, 0, stream>>>(x, f_offs, f_csr, out);
    mlp_valu_kernel<<<(N_NODES + 31) / 32, 256, 0, stream>>>(out, W1, b1, W2,
                                                             b2);
    bn_stats_kernel<<<1024, 256, 0, stream>>>(out, f_stats);
    bn_scale_kernel<<<1, 128, 0, stream>>>(f_stats, gamma, beta, f_stats + 256);
    bn_apply_kernel<<<2048, 256, 0, stream>>>(out, f_stats + 256);
  } else {
    float* s2 = (float*)d_ws;
    hipMemsetAsync(out, 0, (size_t)N_NODES * DIM * sizeof(float), stream);
    hipMemsetAsync(s2, 0, 768 * sizeof(float), stream);
    scatter_kernel<<<4096, 256, 0, stream>>>(x, ei, out, E_);
    add_x_kernel<<<2048, 256, 0, stream>>>(x, out);
    mlp_valu_kernel<<<(N_NODES + 31) / 32, 256, 0, stream>>>(out, W1, b1, W2,
                                                             b2);
    bn_stats_kernel<<<1024, 256, 0, stream>>>(out, s2);
    bn_scale_kernel<<<1, 128, 0, stream>>>(s2, gamma, beta, s2 + 256);
    bn_apply_kernel<<<2048, 256, 0, stream>>>(out, s2 + 256);
  }
}

// Round 7
// 321.156 us; speedup vs baseline: 17.5490x; 1.3964x over previous
//
#include <hip/hip_runtime.h>

#define N_NODES 100000
#define DIM 128
#define NBUCK 391    // ceil(N/256), bucket = dst>>8 (256 nodes per bucket)
#define CAP 12288    // max edges per bucket in bsort (mean 8187)
#define PT_TILE 8192 // edges per partition block
#define PT_THR 512

typedef unsigned int u32;
typedef unsigned short u16;
typedef __attribute__((ext_vector_type(8))) short bf16x8;
typedef __attribute__((ext_vector_type(4))) float f32x4;

__device__ __forceinline__ float bf16_to_f(u16 v) {
  return __uint_as_float(((u32)v) << 16);
}
__device__ __forceinline__ u16 f_to_bf16(float f) {
  u32 b = __float_as_uint(f);
  b += 0x7fff + ((b >> 16) & 1);  // round-to-nearest-even
  return (u16)(b >> 16);
}

// ======================= prep: conversions =======================
__global__ __launch_bounds__(256) void cvt_x_kernel(const float* __restrict__ x,
                                                    u16* __restrict__ xb) {
  int total = N_NODES * DIM / 4;
  int stride = gridDim.x * blockDim.x;
  for (int i = blockIdx.x * blockDim.x + threadIdx.x; i < total; i += stride) {
    float4 v = reinterpret_cast<const float4*>(x)[i];
    ushort4 o;
    o.x = f_to_bf16(v.x);
    o.y = f_to_bf16(v.y);
    o.z = f_to_bf16(v.z);
    o.w = f_to_bf16(v.w);
    reinterpret_cast<ushort4*>(xb)[i] = o;
  }
}

// Wt[c][k] = bf16(W[k][c]) : B^T image, k-contiguous for MFMA B-fragments.
__global__ void cvt_w_kernel(const float* __restrict__ W, u16* __restrict__ Wt) {
  int id = blockIdx.x * 256 + threadIdx.x;  // id = c*128 + k
  int c = id >> 7, k = id & 127;
  Wt[id] = f_to_bf16(W[k * DIM + c]);
}

// ======================= bucketed CSR build =======================
// Bucket histogram: vectorized int4 reads, LDS-aggregated counts.
__global__ __launch_bounds__(256) void bhist_kernel(const int* __restrict__ ei,
                                                    int* __restrict__ bcnt,
                                                    int E_) {
  __shared__ int lc[NBUCK];
  for (int i = threadIdx.x; i < NBUCK; i += 256) lc[i] = 0;
  __syncthreads();
  const int* dst = ei + E_;
  int G = gridDim.x * blockDim.x;
  int g = blockIdx.x * blockDim.x + threadIdx.x;
  int n4 = E_ >> 2;
  const int4* d4 = (const int4*)dst;
  for (int i = g; i < n4; i += G) {
    int4 v = d4[i];
    atomicAdd(&lc[((u32)v.x) >> 8], 1);
    atomicAdd(&lc[((u32)v.y) >> 8], 1);
    atomicAdd(&lc[((u32)v.z) >> 8], 1);
    atomicAdd(&lc[((u32)v.w) >> 8], 1);
  }
  for (int e = (n4 << 2) + g; e < E_; e += G) atomicAdd(&lc[((u32)dst[e]) >> 8], 1);
  __syncthreads();
  for (int i = threadIdx.x; i < NBUCK; i += 256)
    if (lc[i]) atomicAdd(&bcnt[i], lc[i]);
}

// Exclusive scan over NBUCK counts (one block, 2 elems/thread).
__global__ void bscan_kernel(const int* __restrict__ bcnt,
                             int* __restrict__ boffs, int* __restrict__ gcur) {
  __shared__ int s[256];
  int t = threadIdx.x;
  int v0 = (2 * t < NBUCK) ? bcnt[2 * t] : 0;
  int v1 = (2 * t + 1 < NBUCK) ? bcnt[2 * t + 1] : 0;
  int ts = v0 + v1;
  s[t] = ts;
  __syncthreads();
  for (int o = 1; o < 256; o <<= 1) {
    int u = (t >= o) ? s[t - o] : 0;
    __syncthreads();
    s[t] += u;
    __syncthreads();
  }
  int excl = s[t] - ts;
  if (2 * t <= NBUCK) boffs[2 * t] = excl;
  if (2 * t + 1 <= NBUCK) boffs[2 * t + 1] = excl + v0;
  if (2 * t < NBUCK) gcur[2 * t] = excl;
  if (2 * t + 1 < NBUCK) gcur[2 * t + 1] = excl + v0;
}

// Partition v2: per-tile LDS counting sort, zero residual scatter.
// One block = 8192 edges in registers; bucket-grouped in LDS; coalesced
// run writes to global (one gcur atomic per touched bucket per block).
__global__ __launch_bounds__(PT_THR) void partition_kernel(
    const int* __restrict__ ei, int* __restrict__ gcur,
    u32* __restrict__ packed, int E_) {
  __shared__ u32 keys[PT_TILE];   // 32 KB
  __shared__ u16 bid[PT_TILE];    // 16 KB
  __shared__ int lh[NBUCK];       // histogram (counts, preserved)
  __shared__ int lpos[NBUCK];     // placement cursor
  __shared__ int gpos[NBUCK];     // reserved global base
  __shared__ int ss[PT_THR];      // scan buffer
  const int t = threadIdx.x;
  const int base = blockIdx.x * PT_TILE;
  const int cnt = min(PT_TILE, E_ - base);

  for (int i = t; i < NBUCK; i += PT_THR) lh[i] = 0;
  __syncthreads();

  u32 pk[16];
  int bb[16];
#pragma unroll
  for (int k = 0; k < 16; ++k) {
    int e = base + k * PT_THR + t;
    if (k * PT_THR + t < cnt) {
      int src = ei[e];
      u32 dst = (u32)ei[E_ + e];
      bb[k] = (int)(dst >> 8);
      pk[k] = (u32)src | ((dst & 255u) << 17);
      atomicAdd(&lh[bb[k]], 1);
    } else {
      bb[k] = -1;
    }
  }
  __syncthreads();

  // block scan over NBUCK (<= PT_THR) + global reservation
  int v = (t < NBUCK) ? lh[t] : 0;
  ss[t] = v;
  __syncthreads();
  for (int o = 1; o < PT_THR; o <<= 1) {
    int u = (t >= o) ? ss[t - o] : 0;
    __syncthreads();
    ss[t] += u;
    __syncthreads();
  }
  if (t < NBUCK) {
    lpos[t] = ss[t] - v;  // exclusive prefix within tile
    if (v > 0) gpos[t] = atomicAdd(&gcur[t], v);
  }
  __syncthreads();

  // bucket-grouped placement in LDS
#pragma unroll
  for (int k = 0; k < 16; ++k) {
    if (bb[k] >= 0) {
      int p = atomicAdd(&lpos[bb[k]], 1);
      keys[p] = pk[k];
      bid[p] = (u16)bb[k];
    }
  }
  __syncthreads();

  // coalesced run write-out: consecutive i within a bucket -> consecutive
  // global addresses (runs avg ~21 words).
  for (int i = t; i < cnt; i += PT_THR) {
    int b = bid[i];
    int startb = lpos[b] - lh[b];  // == exclusive prefix
    packed[gpos[b] + (i - startb)] = keys[i];
  }
}

// Per-bucket counting sort in LDS -> exact CSR (in place on `packed`) +
// per-node offsets. Global reads/writes fully coalesced.
__global__ __launch_bounds__(256) void bsort_kernel(u32* __restrict__ packed,
                                                    const int* __restrict__ boffs,
                                                    int* __restrict__ offs,
                                                    int E_) {
  __shared__ u32 sorted_[CAP];  // 48 KB
  __shared__ int hist[256], cur[256], ss[256];
  const int b = blockIdx.x, t = threadIdx.x;
  int base = boffs[b];
  int cnt = boffs[b + 1] - base;
  if (cnt > CAP) cnt = CAP;  // statistically unreachable guard
  hist[t] = 0;
  __syncthreads();
  for (int i = t; i < cnt; i += 256) atomicAdd(&hist[packed[base + i] >> 17], 1);
  __syncthreads();
  int hv = hist[t];
  ss[t] = hv;
  __syncthreads();
  for (int o = 1; o < 256; o <<= 1) {
    int u = (t >= o) ? ss[t - o] : 0;
    __syncthreads();
    ss[t] += u;
    __syncthreads();
  }
  int excl = ss[t] - hv;
  cur[t] = excl;
  __syncthreads();
  for (int i = t; i < cnt; i += 256) {
    u32 v = packed[base + i];
    int p = atomicAdd(&cur[v >> 17], 1);
    sorted_[p] = v & 0x1FFFFu;
  }
  __syncthreads();
  for (int i = t; i < cnt; i += 256) packed[base + i] = sorted_[i];
  int node = b * 256 + t;
  if (node < N_NODES) offs[node] = base + excl;
  if (b == 0 && t == 0) offs[N_NODES] = E_;
}

// ======================= Gather (bf16 rows, fp32 accum) ==================
// One wave per node; lane holds 2 columns packed in one u32. 8-deep ILP.
__global__ __launch_bounds__(256) void gather_bf16_kernel(
    const u32* __restrict__ xb, const int* __restrict__ offs,
    const int* __restrict__ csr, u32* __restrict__ hb) {
  int n = blockIdx.x * 4 + (threadIdx.x >> 6);
  int lane = threadIdx.x & 63;
  int beg = offs[n], end = offs[n + 1];
  u32 p = xb[(size_t)n * 64 + lane];
  float a0 = bf16_to_f((u16)(p & 0xffff));
  float a1 = bf16_to_f((u16)(p >> 16));
  float b0 = 0.f, b1 = 0.f, c0 = 0.f, c1 = 0.f, d0 = 0.f, d1 = 0.f;
  int j = beg;
  for (; j + 8 <= end; j += 8) {
    int s0 = csr[j], s1 = csr[j + 1], s2 = csr[j + 2], s3 = csr[j + 3];
    int s4 = csr[j + 4], s5 = csr[j + 5], s6 = csr[j + 6], s7 = csr[j + 7];
    u32 q0 = xb[(size_t)s0 * 64 + lane];
    u32 q1 = xb[(size_t)s1 * 64 + lane];
    u32 q2 = xb[(size_t)s2 * 64 + lane];
    u32 q3 = xb[(size_t)s3 * 64 + lane];
    u32 q4 = xb[(size_t)s4 * 64 + lane];
    u32 q5 = xb[(size_t)s5 * 64 + lane];
    u32 q6 = xb[(size_t)s6 * 64 + lane];
    u32 q7 = xb[(size_t)s7 * 64 + lane];
    a0 += bf16_to_f((u16)(q0 & 0xffff));
    a1 += bf16_to_f((u16)(q0 >> 16));
    b0 += bf16_to_f((u16)(q1 & 0xffff));
    b1 += bf16_to_f((u16)(q1 >> 16));
    c0 += bf16_to_f((u16)(q2 & 0xffff));
    c1 += bf16_to_f((u16)(q2 >> 16));
    d0 += bf16_to_f((u16)(q3 & 0xffff));
    d1 += bf16_to_f((u16)(q3 >> 16));
    a0 += bf16_to_f((u16)(q4 & 0xffff));
    a1 += bf16_to_f((u16)(q4 >> 16));
    b0 += bf16_to_f((u16)(q5 & 0xffff));
    b1 += bf16_to_f((u16)(q5 >> 16));
    c0 += bf16_to_f((u16)(q6 & 0xffff));
    c1 += bf16_to_f((u16)(q6 >> 16));
    d0 += bf16_to_f((u16)(q7 & 0xffff));
    d1 += bf16_to_f((u16)(q7 >> 16));
  }
  for (; j < end; ++j) {
    u32 q = xb[(size_t)csr[j] * 64 + lane];
    a0 += bf16_to_f((u16)(q & 0xffff));
    a1 += bf16_to_f((u16)(q >> 16));
  }
  a0 += b0 + c0 + d0;
  a1 += b1 + c1 + d1;
  hb[(size_t)n * 64 + lane] = ((u32)f_to_bf16(a1) << 16) | (u32)f_to_bf16(a0);
}

// ======================= MFMA MLP =======================
__global__ __launch_bounds__(256) void mlp_mfma_kernel(
    const u16* __restrict__ hb, const u16* __restrict__ Wt1,
    const u16* __restrict__ Wt2, const float* __restrict__ b1,
    const float* __restrict__ b2, float* __restrict__ out) {
  __shared__ u16 sH1[4][16 * DIM];  // 16 KB total, per-wave slab
  const int tid = threadIdx.x;
  const int wv = tid >> 6;
  const int lane = tid & 63;
  const int lr = lane & 15;
  const int lq = lane >> 4;
  const int row0 = blockIdx.x * 64 + wv * 16;

  // ---- layer 1 ----
  bf16x8 a[4];
  {
    int r = row0 + lr;
    if (r > N_NODES - 1) r = N_NODES - 1;
#pragma unroll
    for (int ks = 0; ks < 4; ++ks)
      a[ks] = *reinterpret_cast<const bf16x8*>(hb + (size_t)r * DIM + ks * 32 +
                                               lq * 8);
  }
  f32x4 acc[8];
#pragma unroll
  for (int ct = 0; ct < 8; ++ct) {
    f32x4 c = {0.f, 0.f, 0.f, 0.f};
#pragma unroll
    for (int ks = 0; ks < 4; ++ks) {
      bf16x8 b = *reinterpret_cast<const bf16x8*>(
          Wt1 + (ct * 16 + lr) * DIM + ks * 32 + lq * 8);
      c = __builtin_amdgcn_mfma_f32_16x16x32_bf16(a[ks], b, c, 0, 0, 0);
    }
    acc[ct] = c;
  }
  char* slab = reinterpret_cast<char*>(&sH1[wv][0]);
#pragma unroll
  for (int ct = 0; ct < 8; ++ct) {
    int c = ct * 16 + lr;
    float bias = b1[c];
#pragma unroll
    for (int j = 0; j < 4; ++j) {
      int rl = lq * 4 + j;
      float y = fmaxf(acc[ct][j] + bias, 0.f);
      int byte = rl * 256 + ((c * 2) ^ ((rl & 7) << 4));
      *reinterpret_cast<u16*>(slab + byte) = f_to_bf16(y);
    }
  }
  __syncthreads();

  // ---- layer 2 ----
  bf16x8 a2[4];
#pragma unroll
  for (int ks = 0; ks < 4; ++ks) {
    int byte = lr * 256 + (((ks * 32 + lq * 8) * 2) ^ ((lr & 7) << 4));
    a2[ks] = *reinterpret_cast<const bf16x8*>(slab + byte);
  }
#pragma unroll
  for (int ct = 0; ct < 8; ++ct) {
    f32x4 c = {0.f, 0.f, 0.f, 0.f};
#pragma unroll
    for (int ks = 0; ks < 4; ++ks) {
      bf16x8 b = *reinterpret_cast<const bf16x8*>(
          Wt2 + (ct * 16 + lr) * DIM + ks * 32 + lq * 8);
      c = __builtin_amdgcn_mfma_f32_16x16x32_bf16(a2[ks], b, c, 0, 0, 0);
    }
    acc[ct] = c;
  }
#pragma unroll
  for (int ct = 0; ct < 8; ++ct) {
    int c = ct * 16 + lr;
    float bias = b2[c];
#pragma unroll
    for (int j = 0; j < 4; ++j) {
      int r = row0 + lq * 4 + j;
      if (r < N_NODES)
        out[(size_t)r * DIM + c] = fmaxf(acc[ct][j] + bias, 0.f);
    }
  }
}

// ======================= BatchNorm =======================
__global__ __launch_bounds__(256) void bn_stats_kernel(
    const float* __restrict__ h, float* __restrict__ stats) {
  int col = threadIdx.x & 127;
  int rsub = threadIdx.x >> 7;
  int rstep = gridDim.x * 2;
  float s = 0.f, ss = 0.f;
  for (int r = blockIdx.x * 2 + rsub; r < N_NODES; r += rstep) {
    float v = h[(size_t)r * DIM + col];
    s += v;
    ss += v * v;
  }
  __shared__ float ls[256], lss[256];
  ls[threadIdx.x] = s;
  lss[threadIdx.x] = ss;
  __syncthreads();
  if (threadIdx.x < 128) {
    atomicAdd(&stats[col], ls[threadIdx.x] + ls[threadIdx.x + 128]);
    atomicAdd(&stats[DIM + col], lss[threadIdx.x] + lss[threadIdx.x + 128]);
  }
}

__global__ void bn_scale_kernel(const float* __restrict__ stats,
                                const float* __restrict__ gamma,
                                const float* __restrict__ beta,
                                float* __restrict__ sc) {
  int c = threadIdx.x;  // 128
  float mean = stats[c] / (float)N_NODES;
  float var = stats[DIM + c] / (float)N_NODES - mean * mean;
  float scale = gamma[c] * rsqrtf(var + 1e-5f);
  sc[c] = scale;
  sc[DIM + c] = beta[c] - mean * scale;
}

__global__ __launch_bounds__(256) void bn_apply_kernel(
    float* __restrict__ h, const float* __restrict__ sc) {
  size_t total = (size_t)N_NODES * DIM / 4;
  size_t stride = (size_t)gridDim.x * blockDim.x;
  for (size_t i = (size_t)blockIdx.x * blockDim.x + threadIdx.x; i < total;
       i += stride) {
    float4 v = reinterpret_cast<float4*>(h)[i];
    int c = (int)((i * 4) & 127);
    v.x = v.x * sc[c + 0] + sc[DIM + c + 0];
    v.y = v.y * sc[c + 1] + sc[DIM + c + 1];
    v.z = v.z * sc[c + 2] + sc[DIM + c + 2];
    v.w = v.w * sc[c + 3] + sc[DIM + c + 3];
    reinterpret_cast<float4*>(h)[i] = v;
  }
}

// ======================= Fallback kernels =======================
__global__ __launch_bounds__(256) void hist_kernel(const int* __restrict__ ei,
                                                   int* __restrict__ deg,
                                                   int E_) {
  int stride = gridDim.x * blockDim.x;
  for (int e = blockIdx.x * blockDim.x + threadIdx.x; e < E_; e += stride)
    atomicAdd(&deg[ei[E_ + e]], 1);
}

__global__ __launch_bounds__(256) void scan_block_kernel(
    const int* __restrict__ deg, int* __restrict__ offs,
    int* __restrict__ partials, int n) {
  const int tid = threadIdx.x;
  int g = blockIdx.x * 1024 + tid * 4;
  int v0 = (g + 0 < n) ? deg[g + 0] : 0;
  int v1 = (g + 1 < n) ? deg[g + 1] : 0;
  int v2 = (g + 2 < n) ? deg[g + 2] : 0;
  int v3 = (g + 3 < n) ? deg[g + 3] : 0;
  int tsum = v0 + v1 + v2 + v3;
  __shared__ int s[256];
  s[tid] = tsum;
  __syncthreads();
  for (int off = 1; off < 256; off <<= 1) {
    int t = (tid >= off) ? s[tid - off] : 0;
    __syncthreads();
    s[tid] += t;
    __syncthreads();
  }
  int excl = s[tid] - tsum;
  if (g + 0 < n) offs[g + 0] = excl;
  if (g + 1 < n) offs[g + 1] = excl + v0;
  if (g + 2 < n) offs[g + 2] = excl + v0 + v1;
  if (g + 3 < n) offs[g + 3] = excl + v0 + v1 + v2;
  if (tid == 255) partials[blockIdx.x] = s[255];
}

__global__ void scan_partials_kernel(int* __restrict__ partials, int nb) {
  const int tid = threadIdx.x;
  int v = (tid < nb) ? partials[tid] : 0;
  __shared__ int s[128];
  s[tid] = v;
  __syncthreads();
  for (int off = 1; off < 128; off <<= 1) {
    int t = (tid >= off) ? s[tid - off] : 0;
    __syncthreads();
    s[tid] += t;
    __syncthreads();
  }
  if (tid < nb) partials[tid] = s[tid] - v;
}

__global__ __launch_bounds__(256) void scan_add_kernel(
    int* __restrict__ offs, int* __restrict__ cursor,
    const int* __restrict__ partials, int n, int E_) {
  int g = blockIdx.x * blockDim.x + threadIdx.x;
  if (g < n) {
    int v = offs[g] + partials[g >> 10];
    offs[g] = v;
    cursor[g] = v;
  }
  if (g == 0) offs[n] = E_;
}

__global__ __launch_bounds__(256) void fill_kernel(const int* __restrict__ ei,
                                                   int* __restrict__ cursor,
                                                   int* __restrict__ csr,
                                                   int E_) {
  const int G = gridDim.x * blockDim.x;
  int g = blockIdx.x * blockDim.x + threadIdx.x;
  for (long long base = g; base < E_; base += (long long)G * 8) {
    int src[8], dst[8], pos[8];
#pragma unroll
    for (int k = 0; k < 8; ++k) {
      long long e = base + (long long)k * G;
      src[k] = (e < E_) ? ei[e] : -1;
      dst[k] = (e < E_) ? ei[E_ + e] : 0;
    }
#pragma unroll
    for (int k = 0; k < 8; ++k)
      if (src[k] >= 0) pos[k] = atomicAdd(&cursor[dst[k]], 1);
#pragma unroll
    for (int k = 0; k < 8; ++k)
      if (src[k] >= 0) csr[pos[k]] = src[k];
  }
}

__global__ __launch_bounds__(128) void gather_f32_kernel(
    const float* __restrict__ x, const int* __restrict__ offs,
    const int* __restrict__ csr, float* __restrict__ h) {
  int n = blockIdx.x;
  int c = threadIdx.x;
  int beg = offs[n], end = offs[n + 1];
  float acc = x[(size_t)n * DIM + c];
  for (int j = beg; j < end; ++j) acc += x[(size_t)csr[j] * DIM + c];
  h[(size_t)n * DIM + c] = acc;
}

__global__ __launch_bounds__(256) void scatter_kernel(
    const float* __restrict__ x, const int* __restrict__ ei,
    float* __restrict__ h, int E_) {
  long long total = (long long)E_ * 32;
  long long stride = (long long)gridDim.x * blockDim.x;
  for (long long idx = (long long)blockIdx.x * blockDim.x + threadIdx.x;
       idx < total; idx += stride) {
    int e = (int)(idx >> 5);
    int q = (int)(idx & 31);
    float4 v =
        *reinterpret_cast<const float4*>(x + (size_t)ei[e] * DIM + q * 4);
    float* p = h + (size_t)ei[E_ + e] * DIM + q * 4;
    atomicAdd(p + 0, v.x);
    atomicAdd(p + 1, v.y);
    atomicAdd(p + 2, v.z);
    atomicAdd(p + 3, v.w);
  }
}

__global__ __launch_bounds__(256) void add_x_kernel(const float* __restrict__ x,
                                                    float* __restrict__ h) {
  size_t total = (size_t)N_NODES * DIM / 4;
  size_t stride = (size_t)gridDim.x * blockDim.x;
  for (size_t i = (size_t)blockIdx.x * blockDim.x + threadIdx.x; i < total;
       i += stride) {
    float4 v = reinterpret_cast<float4*>(h)[i];
    float4 xv = reinterpret_cast<const float4*>(x)[i];
    v.x += xv.x; v.y += xv.y; v.z += xv.z; v.w += xv.w;
    reinterpret_cast<float4*>(h)[i] = v;
  }
}

__global__ __launch_bounds__(256) void mlp_valu_kernel(
    float* hbuf, const float* __restrict__ W1, const float* __restrict__ b1,
    const float* __restrict__ W2, const float* __restrict__ b2) {
  __shared__ float sW[DIM * DIM];
  __shared__ float sH[32][DIM];
  const int tid = threadIdx.x;
  const int col = tid & 127;
  const int rhalf = tid >> 7;
  const int row0 = blockIdx.x * 32;

  for (int i = tid; i < DIM * DIM; i += 256) sW[i] = W1[i];
  for (int i = tid; i < 32 * DIM; i += 256) {
    int r = i >> 7, c = i & 127;
    sH[r][c] = hbuf[(size_t)(row0 + r) * DIM + c];
  }
  __syncthreads();
  float acc[16];
  float bias = b1[col];
#pragma unroll
  for (int j = 0; j < 16; ++j) acc[j] = bias;
#pragma unroll 4
  for (int k = 0; k < DIM; ++k) {
    float w = sW[k * DIM + col];
#pragma unroll
    for (int j = 0; j < 16; ++j) acc[j] = fmaf(sH[2 * j + rhalf][k], w, acc[j]);
  }
  __syncthreads();
  for (int i = tid; i < DIM * DIM; i += 256) sW[i] = W2[i];
#pragma unroll
  for (int j = 0; j < 16; ++j) sH[2 * j + rhalf][col] = fmaxf(acc[j], 0.f);
  __syncthreads();
  float bias2 = b2[col];
#pragma unroll
  for (int j = 0; j < 16; ++j) acc[j] = bias2;
#pragma unroll 4
  for (int k = 0; k < DIM; ++k) {
    float w = sW[k * DIM + col];
#pragma unroll
    for (int j = 0; j < 16; ++j) acc[j] = fmaf(sH[2 * j + rhalf][k], w, acc[j]);
  }
#pragma unroll
  for (int j = 0; j < 16; ++j)
    hbuf[(size_t)(row0 + 2 * j + rhalf) * DIM + col] = fmaxf(acc[j], 0.f);
}

extern "C" void kernel_launch(void* const* d_in, const int* in_sizes, int n_in,
                              void* d_out, int out_size, void* d_ws,
                              size_t ws_size, hipStream_t stream) {
  const float* x = (const float*)d_in[0];
  const int* ei = (const int*)d_in[1];
  const float* W1 = (const float*)d_in[3];
  const float* b1 = (const float*)d_in[4];
  const float* W2 = (const float*)d_in[5];
  const float* b2 = (const float*)d_in[6];
  const float* gamma = (const float*)d_in[7];
  const float* beta = (const float*)d_in[8];
  float* out = (float*)d_out;
  int E_ = in_sizes[1] / 2;

  // ---- full-path workspace layout (16B-aligned fields) ----
  const size_t XB_B = (size_t)N_NODES * DIM * 2;  // 25.6e6
  char* w = (char*)d_ws;
  size_t off = 0;
  u16* xb = (u16*)(w + off); off += XB_B;
  u16* hb = (u16*)(w + off); off += XB_B;
  u16* Wt1 = (u16*)(w + off); off += 32768;
  u16* Wt2 = (u16*)(w + off); off += 32768;
  u32* packed = (u32*)(w + off); off += (size_t)E_ * 4;      // doubles as csr
  int* offs = (int*)(w + off); off += ((size_t)N_NODES + 4) * 4;
  int* bcnt = (int*)(w + off); off += 1600;                  // NBUCK ints, padded
  float* stats = (float*)(w + off); off += 3072;             // adjacent to bcnt
  int* boffs = (int*)(w + off); off += 1600;                 // NBUCK+1 ints
  int* gcur = (int*)(w + off); off += 1600;
  size_t need_full = off;

  // ---- CSR-only fallback layout ----
  int* f_offs = (int*)d_ws;
  int* f_cursor = f_offs + N_NODES + 1;
  int* f_partials = f_cursor + N_NODES;
  int* f_csr = f_partials + 128;
  float* f_stats = (float*)(f_csr + E_);
  size_t need_csr = ((size_t)2 * N_NODES + 129 + E_) * 4 + 3072;

  const int nScanBlocks = (N_NODES + 1023) / 1024;  // 98
  const int nEdgeBlocks = (E_ + 2047) / 2048;
  const int nPartBlocks = (E_ + PT_TILE - 1) / PT_TILE;

  if (ws_size >= need_full) {
    cvt_x_kernel<<<2048, 256, 0, stream>>>(x, xb);
    cvt_w_kernel<<<64, 256, 0, stream>>>(W1, Wt1);
    cvt_w_kernel<<<64, 256, 0, stream>>>(W2, Wt2);
    hipMemsetAsync(bcnt, 0, 1600 + 3072, stream);  // bcnt + stats
    bhist_kernel<<<512, 256, 0, stream>>>(ei, bcnt, E_);
    bscan_kernel<<<1, 256, 0, stream>>>(bcnt, boffs, gcur);
    partition_kernel<<<nPartBlocks, PT_THR, 0, stream>>>(ei, gcur, packed, E_);
    bsort_kernel<<<NBUCK, 256, 0, stream>>>(packed, boffs, offs, E_);
    gather_bf16_kernel<<<N_NODES / 4, 256, 0, stream>>>((const u32*)xb, offs,
                                                        (const int*)packed,
                                                        (u32*)hb);
    mlp_mfma_kernel<<<(N_NODES + 63) / 64, 256, 0, stream>>>(hb, Wt1, Wt2, b1,
                                                             b2, out);
    bn_stats_kernel<<<1024, 256, 0, stream>>>(out, stats);
    bn_scale_kernel<<<1, 128, 0, stream>>>(stats, gamma, beta, stats + 256);
    bn_apply_kernel<<<2048, 256, 0, stream>>>(out, stats + 256);
  } else if (ws_size >= need_csr) {
    hipMemsetAsync(f_cursor, 0, (size_t)N_NODES * sizeof(int), stream);
    hipMemsetAsync(f_stats, 0, 768 * sizeof(float), stream);
    hist_kernel<<<2048, 256, 0, stream>>>(ei, f_cursor, E_);
    scan_block_kernel<<<nScanBlocks, 256, 0, stream>>>(f_cursor, f_offs,
                                                       f_partials, N_NODES);
    scan_partials_kernel<<<1, 128, 0, stream>>>(f_partials, nScanBlocks);
    scan_add_kernel<<<(N_NODES + 255) / 256, 256, 0, stream>>>(
        f_offs, f_cursor, f_partials, N_NODES, E_);
    fill_kernel<<<nEdgeBlocks, 256, 0, stream>>>(ei, f_cursor, f_csr, E_);
    gather_f32_kernel<<<N_NODES, 128, 0, stream>>>(x, f_offs, f_csr, out);
    mlp_valu_kernel<<<(N_NODES + 31) / 32, 256, 0, stream>>>(out, W1, b1, W2,
                                                             b2);
    bn_stats_kernel<<<1024, 256, 0, stream>>>(out, f_stats);
    bn_scale_kernel<<<1, 128, 0, stream>>>(f_stats, gamma, beta, f_stats + 256);
    bn_apply_kernel<<<2048, 256, 0, stream>>>(out, f_stats + 256);
  } else {
    float* s2 = (float*)d_ws;
    hipMemsetAsync(out, 0, (size_t)N_NODES * DIM * sizeof(float), stream);
    hipMemsetAsync(s2, 0, 768 * sizeof(float), stream);
    scatter_kernel<<<4096, 256, 0, stream>>>(x, ei, out, E_);
    add_x_kernel<<<2048, 256, 0, stream>>>(x, out);
    mlp_valu_kernel<<<(N_NODES + 31) / 32, 256, 0, stream>>>(out, W1, b1, W2,
                                                             b2);
    bn_stats_kernel<<<1024, 256, 0, stream>>>(out, s2);
    bn_scale_kernel<<<1, 128, 0, stream>>>(s2, gamma, beta, s2 + 256);
    bn_apply_kernel<<<2048, 256, 0, stream>>>(out, s2 + 256);
  }
}

// Round 8
// 286.540 us; speedup vs baseline: 19.6691x; 1.1208x over previous
//
#include <hip/hip_runtime.h>

#define N_NODES 100000
#define DIM 128
#define NBUCK 391    // ceil(N/256), bucket = dst>>8 (256 nodes per bucket)
#define CAP 12288    // max edges per bucket in bsort (mean 8187)
#define PT_TILE 8192 // edges per partition block
#define PT_THR 512

typedef unsigned int u32;
typedef unsigned short u16;
typedef __attribute__((ext_vector_type(8))) short bf16x8;
typedef __attribute__((ext_vector_type(4))) float f32x4;

__device__ __forceinline__ float bf16_to_f(u16 v) {
  return __uint_as_float(((u32)v) << 16);
}
__device__ __forceinline__ u16 f_to_bf16(float f) {
  u32 b = __float_as_uint(f);
  b += 0x7fff + ((b >> 16) & 1);  // round-to-nearest-even
  return (u16)(b >> 16);
}
__device__ __forceinline__ float blo(u32 q) { return __uint_as_float(q << 16); }
__device__ __forceinline__ float bhi(u32 q) {
  return __uint_as_float(q & 0xffff0000u);
}

// ============== prep: cvt_x + cvt_W1 + cvt_W2 + zero(bcnt,stats) ==========
__global__ __launch_bounds__(256) void prep_kernel(
    const float* __restrict__ x, u16* __restrict__ xb,
    const float* __restrict__ W1, u16* __restrict__ Wt1,
    const float* __restrict__ W2, u16* __restrict__ Wt2,
    int* __restrict__ bcnt, float* __restrict__ stats) {
  int blk = blockIdx.x;
  if (blk < 2048) {
    int total = N_NODES * DIM / 4;
    int stride = 2048 * 256;
    for (int i = blk * 256 + threadIdx.x; i < total; i += stride) {
      float4 v = reinterpret_cast<const float4*>(x)[i];
      ushort4 o;
      o.x = f_to_bf16(v.x);
      o.y = f_to_bf16(v.y);
      o.z = f_to_bf16(v.z);
      o.w = f_to_bf16(v.w);
      reinterpret_cast<ushort4*>(xb)[i] = o;
    }
  } else if (blk < 2112) {
    int id = (blk - 2048) * 256 + threadIdx.x;  // id = c*128 + k
    Wt1[id] = f_to_bf16(W1[(id & 127) * DIM + (id >> 7)]);
  } else if (blk < 2176) {
    int id = (blk - 2112) * 256 + threadIdx.x;
    Wt2[id] = f_to_bf16(W2[(id & 127) * DIM + (id >> 7)]);
  } else {
    int t = threadIdx.x;
    for (int i = t; i < 400; i += 256) bcnt[i] = 0;
    for (int i = t; i < 768; i += 256) stats[i] = 0.f;
  }
}

// ======================= bucketed CSR build =======================
__global__ __launch_bounds__(256) void bhist_kernel(const int* __restrict__ ei,
                                                    int* __restrict__ bcnt,
                                                    int E_) {
  __shared__ int lc[NBUCK];
  for (int i = threadIdx.x; i < NBUCK; i += 256) lc[i] = 0;
  __syncthreads();
  const int* dst = ei + E_;
  int G = gridDim.x * blockDim.x;
  int g = blockIdx.x * blockDim.x + threadIdx.x;
  int n4 = E_ >> 2;
  const int4* d4 = (const int4*)dst;
  for (int i = g; i < n4; i += G) {
    int4 v = d4[i];
    atomicAdd(&lc[((u32)v.x) >> 8], 1);
    atomicAdd(&lc[((u32)v.y) >> 8], 1);
    atomicAdd(&lc[((u32)v.z) >> 8], 1);
    atomicAdd(&lc[((u32)v.w) >> 8], 1);
  }
  for (int e = (n4 << 2) + g; e < E_; e += G)
    atomicAdd(&lc[((u32)dst[e]) >> 8], 1);
  __syncthreads();
  for (int i = threadIdx.x; i < NBUCK; i += 256)
    if (lc[i]) atomicAdd(&bcnt[i], lc[i]);
}

__global__ void bscan_kernel(const int* __restrict__ bcnt,
                             int* __restrict__ boffs, int* __restrict__ gcur) {
  __shared__ int s[256];
  int t = threadIdx.x;
  int v0 = (2 * t < NBUCK) ? bcnt[2 * t] : 0;
  int v1 = (2 * t + 1 < NBUCK) ? bcnt[2 * t + 1] : 0;
  int ts = v0 + v1;
  s[t] = ts;
  __syncthreads();
  for (int o = 1; o < 256; o <<= 1) {
    int u = (t >= o) ? s[t - o] : 0;
    __syncthreads();
    s[t] += u;
    __syncthreads();
  }
  int excl = s[t] - ts;
  if (2 * t <= NBUCK) boffs[2 * t] = excl;
  if (2 * t + 1 <= NBUCK) boffs[2 * t + 1] = excl + v0;
  if (2 * t < NBUCK) gcur[2 * t] = excl;
  if (2 * t + 1 < NBUCK) gcur[2 * t + 1] = excl + v0;
}

// Partition: per-tile LDS counting sort, coalesced run write-out.
__global__ __launch_bounds__(PT_THR) void partition_kernel(
    const int* __restrict__ ei, int* __restrict__ gcur,
    u32* __restrict__ packed, int E_) {
  __shared__ u32 keys[PT_TILE];   // 32 KB
  __shared__ u16 bid[PT_TILE];    // 16 KB
  __shared__ int lh[NBUCK];
  __shared__ int lpos[NBUCK];
  __shared__ int gpos[NBUCK];
  __shared__ int ss[PT_THR];
  const int t = threadIdx.x;
  const int base = blockIdx.x * PT_TILE;
  const int cnt = min(PT_TILE, E_ - base);

  for (int i = t; i < NBUCK; i += PT_THR) lh[i] = 0;
  __syncthreads();

  u32 pk[16];
  int bb[16];
#pragma unroll
  for (int k = 0; k < 16; ++k) {
    int e = base + k * PT_THR + t;
    if (k * PT_THR + t < cnt) {
      int src = ei[e];
      u32 dst = (u32)ei[E_ + e];
      bb[k] = (int)(dst >> 8);
      pk[k] = (u32)src | ((dst & 255u) << 17);
      atomicAdd(&lh[bb[k]], 1);
    } else {
      bb[k] = -1;
    }
  }
  __syncthreads();

  int v = (t < NBUCK) ? lh[t] : 0;
  ss[t] = v;
  __syncthreads();
  for (int o = 1; o < PT_THR; o <<= 1) {
    int u = (t >= o) ? ss[t - o] : 0;
    __syncthreads();
    ss[t] += u;
    __syncthreads();
  }
  if (t < NBUCK) {
    lpos[t] = ss[t] - v;
    if (v > 0) gpos[t] = atomicAdd(&gcur[t], v);
  }
  __syncthreads();

#pragma unroll
  for (int k = 0; k < 16; ++k) {
    if (bb[k] >= 0) {
      int p = atomicAdd(&lpos[bb[k]], 1);
      keys[p] = pk[k];
      bid[p] = (u16)bb[k];
    }
  }
  __syncthreads();

  for (int i = t; i < cnt; i += PT_THR) {
    int b = bid[i];
    int startb = lpos[b] - lh[b];
    packed[gpos[b] + (i - startb)] = keys[i];
  }
}

// Per-bucket counting sort in LDS -> exact CSR + per-node offsets.
__global__ __launch_bounds__(256) void bsort_kernel(u32* __restrict__ packed,
                                                    const int* __restrict__ boffs,
                                                    int* __restrict__ offs,
                                                    int E_) {
  __shared__ u32 sorted_[CAP];  // 48 KB
  __shared__ int hist[256], cur[256], ss[256];
  const int b = blockIdx.x, t = threadIdx.x;
  int base = boffs[b];
  int cnt = boffs[b + 1] - base;
  if (cnt > CAP) cnt = CAP;
  hist[t] = 0;
  __syncthreads();
  for (int i = t; i < cnt; i += 256) atomicAdd(&hist[packed[base + i] >> 17], 1);
  __syncthreads();
  int hv = hist[t];
  ss[t] = hv;
  __syncthreads();
  for (int o = 1; o < 256; o <<= 1) {
    int u = (t >= o) ? ss[t - o] : 0;
    __syncthreads();
    ss[t] += u;
    __syncthreads();
  }
  int excl = ss[t] - hv;
  cur[t] = excl;
  __syncthreads();
  for (int i = t; i < cnt; i += 256) {
    u32 v = packed[base + i];
    int p = atomicAdd(&cur[v >> 17], 1);
    sorted_[p] = v & 0x1FFFFu;
  }
  __syncthreads();
  for (int i = t; i < cnt; i += 256) packed[base + i] = sorted_[i];
  int node = b * 256 + t;
  if (node < N_NODES) offs[node] = base + excl;
  if (b == 0 && t == 0) offs[N_NODES] = E_;
}

// ======================= Gather v3 (16-deep ILP, int4 index loads) ========
__global__ __launch_bounds__(256) void gather_bf16_kernel(
    const u32* __restrict__ xb, const int* __restrict__ offs,
    const int* __restrict__ csr, u32* __restrict__ hb) {
  int n = blockIdx.x * 4 + (threadIdx.x >> 6);
  int lane = threadIdx.x & 63;
  int beg = offs[n], end = offs[n + 1];
  u32 p = xb[(size_t)n * 64 + lane];
  float a0 = blo(p), a1 = bhi(p);
  float b0 = 0.f, b1 = 0.f, c0 = 0.f, c1 = 0.f, d0 = 0.f, d1 = 0.f;
  int j = beg;
  // align j to 4 for int4 index loads
  while (j < end && (j & 3)) {
    u32 q = xb[(size_t)csr[j] * 64 + lane];
    a0 += blo(q);
    a1 += bhi(q);
    ++j;
  }
  for (; j + 16 <= end; j += 16) {
    int4 i0 = *reinterpret_cast<const int4*>(csr + j);
    int4 i1 = *reinterpret_cast<const int4*>(csr + j + 4);
    int4 i2 = *reinterpret_cast<const int4*>(csr + j + 8);
    int4 i3 = *reinterpret_cast<const int4*>(csr + j + 12);
    u32 q0 = xb[(size_t)i0.x * 64 + lane];
    u32 q1 = xb[(size_t)i0.y * 64 + lane];
    u32 q2 = xb[(size_t)i0.z * 64 + lane];
    u32 q3 = xb[(size_t)i0.w * 64 + lane];
    u32 q4 = xb[(size_t)i1.x * 64 + lane];
    u32 q5 = xb[(size_t)i1.y * 64 + lane];
    u32 q6 = xb[(size_t)i1.z * 64 + lane];
    u32 q7 = xb[(size_t)i1.w * 64 + lane];
    u32 q8 = xb[(size_t)i2.x * 64 + lane];
    u32 q9 = xb[(size_t)i2.y * 64 + lane];
    u32 qa = xb[(size_t)i2.z * 64 + lane];
    u32 qb = xb[(size_t)i2.w * 64 + lane];
    u32 qc = xb[(size_t)i3.x * 64 + lane];
    u32 qd = xb[(size_t)i3.y * 64 + lane];
    u32 qe = xb[(size_t)i3.z * 64 + lane];
    u32 qf = xb[(size_t)i3.w * 64 + lane];
    a0 += blo(q0); a1 += bhi(q0);
    b0 += blo(q1); b1 += bhi(q1);
    c0 += blo(q2); c1 += bhi(q2);
    d0 += blo(q3); d1 += bhi(q3);
    a0 += blo(q4); a1 += bhi(q4);
    b0 += blo(q5); b1 += bhi(q5);
    c0 += blo(q6); c1 += bhi(q6);
    d0 += blo(q7); d1 += bhi(q7);
    a0 += blo(q8); a1 += bhi(q8);
    b0 += blo(q9); b1 += bhi(q9);
    c0 += blo(qa); c1 += bhi(qa);
    d0 += blo(qb); d1 += bhi(qb);
    a0 += blo(qc); a1 += bhi(qc);
    b0 += blo(qd); b1 += bhi(qd);
    c0 += blo(qe); c1 += bhi(qe);
    d0 += blo(qf); d1 += bhi(qf);
  }
  for (; j + 4 <= end; j += 4) {
    int4 i0 = *reinterpret_cast<const int4*>(csr + j);
    u32 q0 = xb[(size_t)i0.x * 64 + lane];
    u32 q1 = xb[(size_t)i0.y * 64 + lane];
    u32 q2 = xb[(size_t)i0.z * 64 + lane];
    u32 q3 = xb[(size_t)i0.w * 64 + lane];
    a0 += blo(q0); a1 += bhi(q0);
    b0 += blo(q1); b1 += bhi(q1);
    c0 += blo(q2); c1 += bhi(q2);
    d0 += blo(q3); d1 += bhi(q3);
  }
  for (; j < end; ++j) {
    u32 q = xb[(size_t)csr[j] * 64 + lane];
    a0 += blo(q);
    a1 += bhi(q);
  }
  a0 += b0 + c0 + d0;
  a1 += b1 + c1 + d1;
  hb[(size_t)n * 64 + lane] = ((u32)f_to_bf16(a1) << 16) | (u32)f_to_bf16(a0);
}

// ======================= MFMA MLP (+ fused BN partial stats) ==============
__global__ __launch_bounds__(256) void mlp_mfma_kernel(
    const u16* __restrict__ hb, const u16* __restrict__ Wt1,
    const u16* __restrict__ Wt2, const float* __restrict__ b1,
    const float* __restrict__ b2, float* __restrict__ out,
    float* __restrict__ pstats) {
  __shared__ u16 sH1[4][16 * DIM];  // 16 KB
  __shared__ float sS[4][128], sQ[4][128];  // 4 KB
  const int tid = threadIdx.x;
  const int wv = tid >> 6;
  const int lane = tid & 63;
  const int lr = lane & 15;
  const int lq = lane >> 4;
  const int row0 = blockIdx.x * 64 + wv * 16;

  // ---- layer 1 ----
  bf16x8 a[4];
  {
    int r = row0 + lr;
    if (r > N_NODES - 1) r = N_NODES - 1;
#pragma unroll
    for (int ks = 0; ks < 4; ++ks)
      a[ks] = *reinterpret_cast<const bf16x8*>(hb + (size_t)r * DIM + ks * 32 +
                                               lq * 8);
  }
  f32x4 acc[8];
#pragma unroll
  for (int ct = 0; ct < 8; ++ct) {
    f32x4 c = {0.f, 0.f, 0.f, 0.f};
#pragma unroll
    for (int ks = 0; ks < 4; ++ks) {
      bf16x8 b = *reinterpret_cast<const bf16x8*>(
          Wt1 + (ct * 16 + lr) * DIM + ks * 32 + lq * 8);
      c = __builtin_amdgcn_mfma_f32_16x16x32_bf16(a[ks], b, c, 0, 0, 0);
    }
    acc[ct] = c;
  }
  char* slab = reinterpret_cast<char*>(&sH1[wv][0]);
#pragma unroll
  for (int ct = 0; ct < 8; ++ct) {
    int c = ct * 16 + lr;
    float bias = b1[c];
#pragma unroll
    for (int j = 0; j < 4; ++j) {
      int rl = lq * 4 + j;
      float y = fmaxf(acc[ct][j] + bias, 0.f);
      int byte = rl * 256 + ((c * 2) ^ ((rl & 7) << 4));
      *reinterpret_cast<u16*>(slab + byte) = f_to_bf16(y);
    }
  }
  __syncthreads();

  // ---- layer 2 ----
  bf16x8 a2[4];
#pragma unroll
  for (int ks = 0; ks < 4; ++ks) {
    int byte = lr * 256 + (((ks * 32 + lq * 8) * 2) ^ ((lr & 7) << 4));
    a2[ks] = *reinterpret_cast<const bf16x8*>(slab + byte);
  }
#pragma unroll
  for (int ct = 0; ct < 8; ++ct) {
    f32x4 c = {0.f, 0.f, 0.f, 0.f};
#pragma unroll
    for (int ks = 0; ks < 4; ++ks) {
      bf16x8 b = *reinterpret_cast<const bf16x8*>(
          Wt2 + (ct * 16 + lr) * DIM + ks * 32 + lq * 8);
      c = __builtin_amdgcn_mfma_f32_16x16x32_bf16(a2[ks], b, c, 0, 0, 0);
    }
    acc[ct] = c;
  }
  // ---- epilogue: store + per-column partial (s, ss) ----
  float ls[8], lss[8];
#pragma unroll
  for (int ct = 0; ct < 8; ++ct) {
    int c = ct * 16 + lr;
    float bias = b2[c];
    ls[ct] = 0.f;
    lss[ct] = 0.f;
#pragma unroll
    for (int j = 0; j < 4; ++j) {
      int r = row0 + lq * 4 + j;
      float y = fmaxf(acc[ct][j] + bias, 0.f);
      if (r < N_NODES) {
        out[(size_t)r * DIM + c] = y;
        ls[ct] += y;
        lss[ct] += y * y;
      }
    }
  }
#pragma unroll
  for (int ct = 0; ct < 8; ++ct) {
    float s = ls[ct], q = lss[ct];
    s += __shfl_xor(s, 16);
    q += __shfl_xor(q, 16);
    s += __shfl_xor(s, 32);
    q += __shfl_xor(q, 32);
    if (lq == 0) {
      sS[wv][ct * 16 + lr] = s;
      sQ[wv][ct * 16 + lr] = q;
    }
  }
  __syncthreads();
  {
    int t = tid;
    float v;
    if (t < 128)
      v = sS[0][t] + sS[1][t] + sS[2][t] + sS[3][t];
    else
      v = sQ[0][t - 128] + sQ[1][t - 128] + sQ[2][t - 128] + sQ[3][t - 128];
    pstats[(size_t)blockIdx.x * 256 + t] = v;
  }
}

// ======================= BatchNorm =======================
__global__ __launch_bounds__(256) void bn_reduce_kernel(
    const float* __restrict__ pstats, float* __restrict__ stats, int nblk) {
  int t = threadIdx.x;
  float v = 0.f;
  for (int i = blockIdx.x; i < nblk; i += gridDim.x)
    v += pstats[(size_t)i * 256 + t];
  atomicAdd(&stats[t], v);
}

__global__ void bn_scale_kernel(const float* __restrict__ stats,
                                const float* __restrict__ gamma,
                                const float* __restrict__ beta,
                                float* __restrict__ sc) {
  int c = threadIdx.x;  // 128
  float mean = stats[c] / (float)N_NODES;
  float var = stats[DIM + c] / (float)N_NODES - mean * mean;
  float scale = gamma[c] * rsqrtf(var + 1e-5f);
  sc[c] = scale;
  sc[DIM + c] = beta[c] - mean * scale;
}

__global__ __launch_bounds__(256) void bn_apply_kernel(
    float* __restrict__ h, const float* __restrict__ sc) {
  size_t total = (size_t)N_NODES * DIM / 4;
  size_t stride = (size_t)gridDim.x * blockDim.x;
  for (size_t i = (size_t)blockIdx.x * blockDim.x + threadIdx.x; i < total;
       i += stride) {
    float4 v = reinterpret_cast<float4*>(h)[i];
    int c = (int)((i * 4) & 127);
    v.x = v.x * sc[c + 0] + sc[DIM + c + 0];
    v.y = v.y * sc[c + 1] + sc[DIM + c + 1];
    v.z = v.z * sc[c + 2] + sc[DIM + c + 2];
    v.w = v.w * sc[c + 3] + sc[DIM + c + 3];
    reinterpret_cast<float4*>(h)[i] = v;
  }
}

// ======================= Fallback kernels =======================
__global__ __launch_bounds__(256) void hist_kernel(const int* __restrict__ ei,
                                                   int* __restrict__ deg,
                                                   int E_) {
  int stride = gridDim.x * blockDim.x;
  for (int e = blockIdx.x * blockDim.x + threadIdx.x; e < E_; e += stride)
    atomicAdd(&deg[ei[E_ + e]], 1);
}

__global__ __launch_bounds__(256) void scan_block_kernel(
    const int* __restrict__ deg, int* __restrict__ offs,
    int* __restrict__ partials, int n) {
  const int tid = threadIdx.x;
  int g = blockIdx.x * 1024 + tid * 4;
  int v0 = (g + 0 < n) ? deg[g + 0] : 0;
  int v1 = (g + 1 < n) ? deg[g + 1] : 0;
  int v2 = (g + 2 < n) ? deg[g + 2] : 0;
  int v3 = (g + 3 < n) ? deg[g + 3] : 0;
  int tsum = v0 + v1 + v2 + v3;
  __shared__ int s[256];
  s[tid] = tsum;
  __syncthreads();
  for (int off = 1; off < 256; off <<= 1) {
    int t = (tid >= off) ? s[tid - off] : 0;
    __syncthreads();
    s[tid] += t;
    __syncthreads();
  }
  int excl = s[tid] - tsum;
  if (g + 0 < n) offs[g + 0] = excl;
  if (g + 1 < n) offs[g + 1] = excl + v0;
  if (g + 2 < n) offs[g + 2] = excl + v0 + v1;
  if (g + 3 < n) offs[g + 3] = excl + v0 + v1 + v2;
  if (tid == 255) partials[blockIdx.x] = s[255];
}

__global__ void scan_partials_kernel(int* __restrict__ partials, int nb) {
  const int tid = threadIdx.x;
  int v = (tid < nb) ? partials[tid] : 0;
  __shared__ int s[128];
  s[tid] = v;
  __syncthreads();
  for (int off = 1; off < 128; off <<= 1) {
    int t = (tid >= off) ? s[tid - off] : 0;
    __syncthreads();
    s[tid] += t;
    __syncthreads();
  }
  if (tid < nb) partials[tid] = s[tid] - v;
}

__global__ __launch_bounds__(256) void scan_add_kernel(
    int* __restrict__ offs, int* __restrict__ cursor,
    const int* __restrict__ partials, int n, int E_) {
  int g = blockIdx.x * blockDim.x + threadIdx.x;
  if (g < n) {
    int v = offs[g] + partials[g >> 10];
    offs[g] = v;
    cursor[g] = v;
  }
  if (g == 0) offs[n] = E_;
}

__global__ __launch_bounds__(256) void fill_kernel(const int* __restrict__ ei,
                                                   int* __restrict__ cursor,
                                                   int* __restrict__ csr,
                                                   int E_) {
  const int G = gridDim.x * blockDim.x;
  int g = blockIdx.x * blockDim.x + threadIdx.x;
  for (long long base = g; base < E_; base += (long long)G * 8) {
    int src[8], dst[8], pos[8];
#pragma unroll
    for (int k = 0; k < 8; ++k) {
      long long e = base + (long long)k * G;
      src[k] = (e < E_) ? ei[e] : -1;
      dst[k] = (e < E_) ? ei[E_ + e] : 0;
    }
#pragma unroll
    for (int k = 0; k < 8; ++k)
      if (src[k] >= 0) pos[k] = atomicAdd(&cursor[dst[k]], 1);
#pragma unroll
    for (int k = 0; k < 8; ++k)
      if (src[k] >= 0) csr[pos[k]] = src[k];
  }
}

__global__ __launch_bounds__(128) void gather_f32_kernel(
    const float* __restrict__ x, const int* __restrict__ offs,
    const int* __restrict__ csr, float* __restrict__ h) {
  int n = blockIdx.x;
  int c = threadIdx.x;
  int beg = offs[n], end = offs[n + 1];
  float acc = x[(size_t)n * DIM + c];
  for (int j = beg; j < end; ++j) acc += x[(size_t)csr[j] * DIM + c];
  h[(size_t)n * DIM + c] = acc;
}

__global__ __launch_bounds__(256) void scatter_kernel(
    const float* __restrict__ x, const int* __restrict__ ei,
    float* __restrict__ h, int E_) {
  long long total = (long long)E_ * 32;
  long long stride = (long long)gridDim.x * blockDim.x;
  for (long long idx = (long long)blockIdx.x * blockDim.x + threadIdx.x;
       idx < total; idx += stride) {
    int e = (int)(idx >> 5);
    int q = (int)(idx & 31);
    float4 v =
        *reinterpret_cast<const float4*>(x + (size_t)ei[e] * DIM + q * 4);
    float* p = h + (size_t)ei[E_ + e] * DIM + q * 4;
    atomicAdd(p + 0, v.x);
    atomicAdd(p + 1, v.y);
    atomicAdd(p + 2, v.z);
    atomicAdd(p + 3, v.w);
  }
}

__global__ __launch_bounds__(256) void add_x_kernel(const float* __restrict__ x,
                                                    float* __restrict__ h) {
  size_t total = (size_t)N_NODES * DIM / 4;
  size_t stride = (size_t)gridDim.x * blockDim.x;
  for (size_t i = (size_t)blockIdx.x * blockDim.x + threadIdx.x; i < total;
       i += stride) {
    float4 v = reinterpret_cast<float4*>(h)[i];
    float4 xv = reinterpret_cast<const float4*>(x)[i];
    v.x += xv.x; v.y += xv.y; v.z += xv.z; v.w += xv.w;
    reinterpret_cast<float4*>(h)[i] = v;
  }
}

__global__ __launch_bounds__(256) void mlp_valu_kernel(
    float* hbuf, const float* __restrict__ W1, const float* __restrict__ b1,
    const float* __restrict__ W2, const float* __restrict__ b2) {
  __shared__ float sW[DIM * DIM];
  __shared__ float sH[32][DIM];
  const int tid = threadIdx.x;
  const int col = tid & 127;
  const int rhalf = tid >> 7;
  const int row0 = blockIdx.x * 32;

  for (int i = tid; i < DIM * DIM; i += 256) sW[i] = W1[i];
  for (int i = tid; i < 32 * DIM; i += 256) {
    int r = i >> 7, c = i & 127;
    sH[r][c] = hbuf[(size_t)(row0 + r) * DIM + c];
  }
  __syncthreads();
  float acc[16];
  float bias = b1[col];
#pragma unroll
  for (int j = 0; j < 16; ++j) acc[j] = bias;
#pragma unroll 4
  for (int k = 0; k < DIM; ++k) {
    float w = sW[k * DIM + col];
#pragma unroll
    for (int j = 0; j < 16; ++j) acc[j] = fmaf(sH[2 * j + rhalf][k], w, acc[j]);
  }
  __syncthreads();
  for (int i = tid; i < DIM * DIM; i += 256) sW[i] = W2[i];
#pragma unroll
  for (int j = 0; j < 16; ++j) sH[2 * j + rhalf][col] = fmaxf(acc[j], 0.f);
  __syncthreads();
  float bias2 = b2[col];
#pragma unroll
  for (int j = 0; j < 16; ++j) acc[j] = bias2;
#pragma unroll 4
  for (int k = 0; k < DIM; ++k) {
    float w = sW[k * DIM + col];
#pragma unroll
    for (int j = 0; j < 16; ++j) acc[j] = fmaf(sH[2 * j + rhalf][k], w, acc[j]);
  }
#pragma unroll
  for (int j = 0; j < 16; ++j)
    hbuf[(size_t)(row0 + 2 * j + rhalf) * DIM + col] = fmaxf(acc[j], 0.f);
}

__global__ __launch_bounds__(256) void bn_stats_kernel(
    const float* __restrict__ h, float* __restrict__ stats) {
  int col = threadIdx.x & 127;
  int rsub = threadIdx.x >> 7;
  int rstep = gridDim.x * 2;
  float s = 0.f, ss = 0.f;
  for (int r = blockIdx.x * 2 + rsub; r < N_NODES; r += rstep) {
    float v = h[(size_t)r * DIM + col];
    s += v;
    ss += v * v;
  }
  __shared__ float ls[256], lss[256];
  ls[threadIdx.x] = s;
  lss[threadIdx.x] = ss;
  __syncthreads();
  if (threadIdx.x < 128) {
    atomicAdd(&stats[col], ls[threadIdx.x] + ls[threadIdx.x + 128]);
    atomicAdd(&stats[DIM + col], lss[threadIdx.x] + lss[threadIdx.x + 128]);
  }
}

extern "C" void kernel_launch(void* const* d_in, const int* in_sizes, int n_in,
                              void* d_out, int out_size, void* d_ws,
                              size_t ws_size, hipStream_t stream) {
  const float* x = (const float*)d_in[0];
  const int* ei = (const int*)d_in[1];
  const float* W1 = (const float*)d_in[3];
  const float* b1 = (const float*)d_in[4];
  const float* W2 = (const float*)d_in[5];
  const float* b2 = (const float*)d_in[6];
  const float* gamma = (const float*)d_in[7];
  const float* beta = (const float*)d_in[8];
  float* out = (float*)d_out;
  int E_ = in_sizes[1] / 2;

  // ---- full-path workspace layout (16B-aligned fields) ----
  const size_t XB_B = (size_t)N_NODES * DIM * 2;  // 25.6e6
  char* w = (char*)d_ws;
  size_t off = 0;
  u16* xb = (u16*)(w + off); off += XB_B;
  u16* hb = (u16*)(w + off); off += XB_B;
  u16* Wt1 = (u16*)(w + off); off += 32768;
  u16* Wt2 = (u16*)(w + off); off += 32768;
  u32* packed = (u32*)(w + off); off += (size_t)E_ * 4;      // doubles as csr
  int* offs = (int*)(w + off); off += ((size_t)N_NODES + 4) * 4;
  int* bcnt = (int*)(w + off); off += 1600;
  float* stats = (float*)(w + off); off += 3072;
  int* boffs = (int*)(w + off); off += 1600;
  int* gcur = (int*)(w + off); off += 1600;
  size_t need_full = off;
  float* pstats = (float*)xb;  // reuse xb after gather (dead by mlp time)

  // ---- CSR-only fallback layout ----
  int* f_offs = (int*)d_ws;
  int* f_cursor = f_offs + N_NODES + 1;
  int* f_partials = f_cursor + N_NODES;
  int* f_csr = f_partials + 128;
  float* f_stats = (float*)(f_csr + E_);
  size_t need_csr = ((size_t)2 * N_NODES + 129 + E_) * 4 + 3072;

  const int nScanBlocks = (N_NODES + 1023) / 1024;  // 98
  const int nEdgeBlocks = (E_ + 2047) / 2048;
  const int nPartBlocks = (E_ + PT_TILE - 1) / PT_TILE;
  const int nMlpBlocks = (N_NODES + 63) / 64;  // 1563

  if (ws_size >= need_full) {
    prep_kernel<<<2177, 256, 0, stream>>>(x, xb, W1, Wt1, W2, Wt2, bcnt,
                                          stats);
    bhist_kernel<<<512, 256, 0, stream>>>(ei, bcnt, E_);
    bscan_kernel<<<1, 256, 0, stream>>>(bcnt, boffs, gcur);
    partition_kernel<<<nPartBlocks, PT_THR, 0, stream>>>(ei, gcur, packed, E_);
    bsort_kernel<<<NBUCK, 256, 0, stream>>>(packed, boffs, offs, E_);
    gather_bf16_kernel<<<N_NODES / 4, 256, 0, stream>>>((const u32*)xb, offs,
                                                        (const int*)packed,
                                                        (u32*)hb);
    mlp_mfma_kernel<<<nMlpBlocks, 256, 0, stream>>>(hb, Wt1, Wt2, b1, b2, out,
                                                    pstats);
    bn_reduce_kernel<<<32, 256, 0, stream>>>(pstats, stats, nMlpBlocks);
    bn_scale_kernel<<<1, 128, 0, stream>>>(stats, gamma, beta, stats + 256);
    bn_apply_kernel<<<2048, 256, 0, stream>>>(out, stats + 256);
  } else if (ws_size >= need_csr) {
    hipMemsetAsync(f_cursor, 0, (size_t)N_NODES * sizeof(int), stream);
    hipMemsetAsync(f_stats, 0, 768 * sizeof(float), stream);
    hist_kernel<<<2048, 256, 0, stream>>>(ei, f_cursor, E_);
    scan_block_kernel<<<nScanBlocks, 256, 0, stream>>>(f_cursor, f_offs,
                                                       f_partials, N_NODES);
    scan_partials_kernel<<<1, 128, 0, stream>>>(f_partials, nScanBlocks);
    scan_add_kernel<<<(N_NODES + 255) / 256, 256, 0, stream>>>(
        f_offs, f_cursor, f_partials, N_NODES, E_);
    fill_kernel<<<nEdgeBlocks, 256, 0, stream>>>(ei, f_cursor, f_csr, E_);
    gather_f32_kernel<<<N_NODES, 128, 0, stream>>>(x, f_offs, f_csr, out);
    mlp_valu_kernel<<<(N_NODES + 31) / 32, 256, 0, stream>>>(out, W1, b1, W2,
                                                             b2);
    bn_stats_kernel<<<1024, 256, 0, stream>>>(out, f_stats);
    bn_scale_kernel<<<1, 128, 0, stream>>>(f_stats, gamma, beta, f_stats + 256);
    bn_apply_kernel<<<2048, 256, 0, stream>>>(out, f_stats + 256);
  } else {
    float* s2 = (float*)d_ws;
    hipMemsetAsync(out, 0, (size_t)N_NODES * DIM * sizeof(float), stream);
    hipMemsetAsync(s2, 0, 768 * sizeof(float), stream);
    scatter_kernel<<<4096, 256, 0, stream>>>(x, ei, out, E_);
    add_x_kernel<<<2048, 256, 0, stream>>>(x, out);
    mlp_valu_kernel<<<(N_NODES + 31) / 32, 256, 0, stream>>>(out, W1, b1, W2,
                                                             b2);
    bn_stats_kernel<<<1024, 256, 0, stream>>>(out, s2);
    bn_scale_kernel<<<1, 128, 0, stream>>>(s2, gamma, beta, s2 + 256);
    bn_apply_kernel<<<2048, 256, 0, stream>>>(out, s2 + 256);
  }
}

// Round 9
// 284.592 us; speedup vs baseline: 19.8037x; 1.0068x over previous
//
#include <hip/hip_runtime.h>

#define N_NODES 100000
#define DIM 128
#define NBUCK 391    // ceil(N/256), bucket = dst>>8 (256 nodes per bucket)
#define CAP 12288    // max edges per bucket in bsort (mean 8187)
#define PT_TILE 8192 // edges per partition block
#define PT_THR 512

typedef unsigned int u32;
typedef unsigned short u16;
typedef __attribute__((ext_vector_type(8))) short bf16x8;
typedef __attribute__((ext_vector_type(4))) float f32x4;

__device__ __forceinline__ float bf16_to_f(u16 v) {
  return __uint_as_float(((u32)v) << 16);
}
__device__ __forceinline__ u16 f_to_bf16(float f) {
  u32 b = __float_as_uint(f);
  b += 0x7fff + ((b >> 16) & 1);  // round-to-nearest-even
  return (u16)(b >> 16);
}
__device__ __forceinline__ float blo(u32 q) { return __uint_as_float(q << 16); }
__device__ __forceinline__ float bhi(u32 q) {
  return __uint_as_float(q & 0xffff0000u);
}
__device__ __forceinline__ u32 packbf(float lo, float hi) {
  return ((u32)f_to_bf16(hi) << 16) | (u32)f_to_bf16(lo);
}

// ====== prep: cvt_x + cvt_W1 + cvt_W2 + bhist (concurrent sections) ======
__global__ __launch_bounds__(256) void prep_kernel(
    const float* __restrict__ x, u16* __restrict__ xb,
    const float* __restrict__ W1, u16* __restrict__ Wt1,
    const float* __restrict__ W2, u16* __restrict__ Wt2,
    const int* __restrict__ ei, int* __restrict__ bcnt, int E_) {
  int blk = blockIdx.x;
  if (blk < 2048) {
    int total = N_NODES * DIM / 4;
    int stride = 2048 * 256;
    for (int i = blk * 256 + threadIdx.x; i < total; i += stride) {
      float4 v = reinterpret_cast<const float4*>(x)[i];
      ushort4 o;
      o.x = f_to_bf16(v.x);
      o.y = f_to_bf16(v.y);
      o.z = f_to_bf16(v.z);
      o.w = f_to_bf16(v.w);
      reinterpret_cast<ushort4*>(xb)[i] = o;
    }
  } else if (blk < 2112) {
    int id = (blk - 2048) * 256 + threadIdx.x;  // id = c*128 + k
    Wt1[id] = f_to_bf16(W1[(id & 127) * DIM + (id >> 7)]);
  } else if (blk < 2176) {
    int id = (blk - 2112) * 256 + threadIdx.x;
    Wt2[id] = f_to_bf16(W2[(id & 127) * DIM + (id >> 7)]);
  } else {
    // bucket histogram over dst
    __shared__ int lc[NBUCK];
    for (int i = threadIdx.x; i < NBUCK; i += 256) lc[i] = 0;
    __syncthreads();
    const int* dst = ei + E_;
    int G = 512 * 256;
    int g = (blk - 2176) * 256 + threadIdx.x;
    int n4 = E_ >> 2;
    const int4* d4 = (const int4*)dst;
    for (int i = g; i < n4; i += G) {
      int4 v = d4[i];
      atomicAdd(&lc[((u32)v.x) >> 8], 1);
      atomicAdd(&lc[((u32)v.y) >> 8], 1);
      atomicAdd(&lc[((u32)v.z) >> 8], 1);
      atomicAdd(&lc[((u32)v.w) >> 8], 1);
    }
    for (int e = (n4 << 2) + g; e < E_; e += G)
      atomicAdd(&lc[((u32)dst[e]) >> 8], 1);
    __syncthreads();
    for (int i = threadIdx.x; i < NBUCK; i += 256)
      if (lc[i]) atomicAdd(&bcnt[i], lc[i]);
  }
}

__global__ void bscan_kernel(const int* __restrict__ bcnt,
                             int* __restrict__ boffs, int* __restrict__ gcur) {
  __shared__ int s[256];
  int t = threadIdx.x;
  int v0 = (2 * t < NBUCK) ? bcnt[2 * t] : 0;
  int v1 = (2 * t + 1 < NBUCK) ? bcnt[2 * t + 1] : 0;
  int ts = v0 + v1;
  s[t] = ts;
  __syncthreads();
  for (int o = 1; o < 256; o <<= 1) {
    int u = (t >= o) ? s[t - o] : 0;
    __syncthreads();
    s[t] += u;
    __syncthreads();
  }
  int excl = s[t] - ts;
  if (2 * t <= NBUCK) boffs[2 * t] = excl;
  if (2 * t + 1 <= NBUCK) boffs[2 * t + 1] = excl + v0;
  if (2 * t < NBUCK) gcur[2 * t] = excl;
  if (2 * t + 1 < NBUCK) gcur[2 * t + 1] = excl + v0;
}

// Partition: per-tile LDS counting sort, coalesced run write-out.
__global__ __launch_bounds__(PT_THR) void partition_kernel(
    const int* __restrict__ ei, int* __restrict__ gcur,
    u32* __restrict__ packed, int E_) {
  __shared__ u32 keys[PT_TILE];   // 32 KB
  __shared__ u16 bid[PT_TILE];    // 16 KB
  __shared__ int lh[NBUCK];
  __shared__ int lpos[NBUCK];
  __shared__ int gpos[NBUCK];
  __shared__ int ss[PT_THR];
  const int t = threadIdx.x;
  const int base = blockIdx.x * PT_TILE;
  const int cnt = min(PT_TILE, E_ - base);

  for (int i = t; i < NBUCK; i += PT_THR) lh[i] = 0;
  __syncthreads();

  u32 pk[16];
  int bb[16];
#pragma unroll
  for (int k = 0; k < 16; ++k) {
    int e = base + k * PT_THR + t;
    if (k * PT_THR + t < cnt) {
      int src = ei[e];
      u32 dst = (u32)ei[E_ + e];
      bb[k] = (int)(dst >> 8);
      pk[k] = (u32)src | ((dst & 255u) << 17);
      atomicAdd(&lh[bb[k]], 1);
    } else {
      bb[k] = -1;
    }
  }
  __syncthreads();

  int v = (t < NBUCK) ? lh[t] : 0;
  ss[t] = v;
  __syncthreads();
  for (int o = 1; o < PT_THR; o <<= 1) {
    int u = (t >= o) ? ss[t - o] : 0;
    __syncthreads();
    ss[t] += u;
    __syncthreads();
  }
  if (t < NBUCK) {
    lpos[t] = ss[t] - v;
    if (v > 0) gpos[t] = atomicAdd(&gcur[t], v);
  }
  __syncthreads();

#pragma unroll
  for (int k = 0; k < 16; ++k) {
    if (bb[k] >= 0) {
      int p = atomicAdd(&lpos[bb[k]], 1);
      keys[p] = pk[k];
      bid[p] = (u16)bb[k];
    }
  }
  __syncthreads();

  for (int i = t; i < cnt; i += PT_THR) {
    int b = bid[i];
    int startb = lpos[b] - lh[b];
    packed[gpos[b] + (i - startb)] = keys[i];
  }
}

// Per-bucket counting sort in LDS -> exact CSR + per-node offsets.
__global__ __launch_bounds__(256) void bsort_kernel(u32* __restrict__ packed,
                                                    const int* __restrict__ boffs,
                                                    int* __restrict__ offs,
                                                    int E_) {
  __shared__ u32 sorted_[CAP];  // 48 KB
  __shared__ int hist[256], cur[256], ss[256];
  const int b = blockIdx.x, t = threadIdx.x;
  int base = boffs[b];
  int cnt = boffs[b + 1] - base;
  if (cnt > CAP) cnt = CAP;
  hist[t] = 0;
  __syncthreads();
  for (int i = t; i < cnt; i += 256) atomicAdd(&hist[packed[base + i] >> 17], 1);
  __syncthreads();
  int hv = hist[t];
  ss[t] = hv;
  __syncthreads();
  for (int o = 1; o < 256; o <<= 1) {
    int u = (t >= o) ? ss[t - o] : 0;
    __syncthreads();
    ss[t] += u;
    __syncthreads();
  }
  int excl = ss[t] - hv;
  cur[t] = excl;
  __syncthreads();
  for (int i = t; i < cnt; i += 256) {
    u32 v = packed[base + i];
    int p = atomicAdd(&cur[v >> 17], 1);
    sorted_[p] = v & 0x1FFFFu;
  }
  __syncthreads();
  for (int i = t; i < cnt; i += 256) packed[base + i] = sorted_[i];
  int node = b * 256 + t;
  if (node < N_NODES) offs[node] = base + excl;
  if (b == 0 && t == 0) offs[N_NODES] = E_;
}

// ========== Gather v4: 16B/lane loads, 16 lanes/row, 4 edges/wave =========
// Wave per node. Group g = lane>>4 takes edges beg+g, beg+g+4, ... ; lane
// l = lane&15 loads 16B (8 bf16 cols 8l..8l+7). Final 2-step shfl reduce.
__global__ __launch_bounds__(256) void gather_bf16_kernel(
    const uint4* __restrict__ xb4, const int* __restrict__ offs,
    const int* __restrict__ csr, uint4* __restrict__ hb4) {
  int n = blockIdx.x * 4 + (threadIdx.x >> 6);
  int lane = threadIdx.x & 63;
  int g = lane >> 4;
  int l = lane & 15;
  int beg = offs[n], end = offs[n + 1];
  float a0 = 0.f, a1 = 0.f, a2 = 0.f, a3 = 0.f;
  float a4 = 0.f, a5 = 0.f, a6 = 0.f, a7 = 0.f;
  if (g == 0) {  // self row
    uint4 q = xb4[(size_t)n * 16 + l];
    a0 = blo(q.x); a1 = bhi(q.x);
    a2 = blo(q.y); a3 = bhi(q.y);
    a4 = blo(q.z); a5 = bhi(q.z);
    a6 = blo(q.w); a7 = bhi(q.w);
  }
  int j = beg + g;
  // 4-deep ILP within group (covers 16 edges per wave iteration)
  for (; j + 12 < end; j += 16) {
    int s0 = csr[j], s1 = csr[j + 4], s2 = csr[j + 8], s3 = csr[j + 12];
    uint4 q0 = xb4[(size_t)s0 * 16 + l];
    uint4 q1 = xb4[(size_t)s1 * 16 + l];
    uint4 q2 = xb4[(size_t)s2 * 16 + l];
    uint4 q3 = xb4[(size_t)s3 * 16 + l];
    a0 += blo(q0.x); a1 += bhi(q0.x);
    a2 += blo(q0.y); a3 += bhi(q0.y);
    a4 += blo(q0.z); a5 += bhi(q0.z);
    a6 += blo(q0.w); a7 += bhi(q0.w);
    a0 += blo(q1.x); a1 += bhi(q1.x);
    a2 += blo(q1.y); a3 += bhi(q1.y);
    a4 += blo(q1.z); a5 += bhi(q1.z);
    a6 += blo(q1.w); a7 += bhi(q1.w);
    a0 += blo(q2.x); a1 += bhi(q2.x);
    a2 += blo(q2.y); a3 += bhi(q2.y);
    a4 += blo(q2.z); a5 += bhi(q2.z);
    a6 += blo(q2.w); a7 += bhi(q2.w);
    a0 += blo(q3.x); a1 += bhi(q3.x);
    a2 += blo(q3.y); a3 += bhi(q3.y);
    a4 += blo(q3.z); a5 += bhi(q3.z);
    a6 += blo(q3.w); a7 += bhi(q3.w);
  }
  for (; j < end; j += 4) {
    uint4 q = xb4[(size_t)csr[j] * 16 + l];
    a0 += blo(q.x); a1 += bhi(q.x);
    a2 += blo(q.y); a3 += bhi(q.y);
    a4 += blo(q.z); a5 += bhi(q.z);
    a6 += blo(q.w); a7 += bhi(q.w);
  }
  // reduce across the 4 groups (lanes l, l+16, l+32, l+48)
  a0 += __shfl_xor(a0, 16); a1 += __shfl_xor(a1, 16);
  a2 += __shfl_xor(a2, 16); a3 += __shfl_xor(a3, 16);
  a4 += __shfl_xor(a4, 16); a5 += __shfl_xor(a5, 16);
  a6 += __shfl_xor(a6, 16); a7 += __shfl_xor(a7, 16);
  a0 += __shfl_xor(a0, 32); a1 += __shfl_xor(a1, 32);
  a2 += __shfl_xor(a2, 32); a3 += __shfl_xor(a3, 32);
  a4 += __shfl_xor(a4, 32); a5 += __shfl_xor(a5, 32);
  a6 += __shfl_xor(a6, 32); a7 += __shfl_xor(a7, 32);
  if (g == 0) {
    uint4 o;
    o.x = packbf(a0, a1);
    o.y = packbf(a2, a3);
    o.z = packbf(a4, a5);
    o.w = packbf(a6, a7);
    hb4[(size_t)n * 16 + l] = o;
  }
}

// ======================= MFMA MLP (+ fused BN partial stats) ==============
__global__ __launch_bounds__(256) void mlp_mfma_kernel(
    const u16* __restrict__ hb, const u16* __restrict__ Wt1,
    const u16* __restrict__ Wt2, const float* __restrict__ b1,
    const float* __restrict__ b2, float* __restrict__ out,
    float* __restrict__ pstats) {
  __shared__ u16 sH1[4][16 * DIM];  // 16 KB
  __shared__ float sS[4][128], sQ[4][128];  // 4 KB
  const int tid = threadIdx.x;
  const int wv = tid >> 6;
  const int lane = tid & 63;
  const int lr = lane & 15;
  const int lq = lane >> 4;
  const int row0 = blockIdx.x * 64 + wv * 16;

  // ---- layer 1 ----
  bf16x8 a[4];
  {
    int r = row0 + lr;
    if (r > N_NODES - 1) r = N_NODES - 1;
#pragma unroll
    for (int ks = 0; ks < 4; ++ks)
      a[ks] = *reinterpret_cast<const bf16x8*>(hb + (size_t)r * DIM + ks * 32 +
                                               lq * 8);
  }
  f32x4 acc[8];
#pragma unroll
  for (int ct = 0; ct < 8; ++ct) {
    f32x4 c = {0.f, 0.f, 0.f, 0.f};
#pragma unroll
    for (int ks = 0; ks < 4; ++ks) {
      bf16x8 b = *reinterpret_cast<const bf16x8*>(
          Wt1 + (ct * 16 + lr) * DIM + ks * 32 + lq * 8);
      c = __builtin_amdgcn_mfma_f32_16x16x32_bf16(a[ks], b, c, 0, 0, 0);
    }
    acc[ct] = c;
  }
  char* slab = reinterpret_cast<char*>(&sH1[wv][0]);
#pragma unroll
  for (int ct = 0; ct < 8; ++ct) {
    int c = ct * 16 + lr;
    float bias = b1[c];
#pragma unroll
    for (int j = 0; j < 4; ++j) {
      int rl = lq * 4 + j;
      float y = fmaxf(acc[ct][j] + bias, 0.f);
      int byte = rl * 256 + ((c * 2) ^ ((rl & 7) << 4));
      *reinterpret_cast<u16*>(slab + byte) = f_to_bf16(y);
    }
  }
  __syncthreads();

  // ---- layer 2 ----
  bf16x8 a2[4];
#pragma unroll
  for (int ks = 0; ks < 4; ++ks) {
    int byte = lr * 256 + (((ks * 32 + lq * 8) * 2) ^ ((lr & 7) << 4));
    a2[ks] = *reinterpret_cast<const bf16x8*>(slab + byte);
  }
#pragma unroll
  for (int ct = 0; ct < 8; ++ct) {
    f32x4 c = {0.f, 0.f, 0.f, 0.f};
#pragma unroll
    for (int ks = 0; ks < 4; ++ks) {
      bf16x8 b = *reinterpret_cast<const bf16x8*>(
          Wt2 + (ct * 16 + lr) * DIM + ks * 32 + lq * 8);
      c = __builtin_amdgcn_mfma_f32_16x16x32_bf16(a2[ks], b, c, 0, 0, 0);
    }
    acc[ct] = c;
  }
  // ---- epilogue: store + per-column partial (s, ss) ----
  float ls[8], lss[8];
#pragma unroll
  for (int ct = 0; ct < 8; ++ct) {
    int c = ct * 16 + lr;
    float bias = b2[c];
    ls[ct] = 0.f;
    lss[ct] = 0.f;
#pragma unroll
    for (int j = 0; j < 4; ++j) {
      int r = row0 + lq * 4 + j;
      float y = fmaxf(acc[ct][j] + bias, 0.f);
      if (r < N_NODES) {
        out[(size_t)r * DIM + c] = y;
        ls[ct] += y;
        lss[ct] += y * y;
      }
    }
  }
#pragma unroll
  for (int ct = 0; ct < 8; ++ct) {
    float s = ls[ct], q = lss[ct];
    s += __shfl_xor(s, 16);
    q += __shfl_xor(q, 16);
    s += __shfl_xor(s, 32);
    q += __shfl_xor(q, 32);
    if (lq == 0) {
      sS[wv][ct * 16 + lr] = s;
      sQ[wv][ct * 16 + lr] = q;
    }
  }
  __syncthreads();
  {
    int t = tid;
    float v;
    if (t < 128)
      v = sS[0][t] + sS[1][t] + sS[2][t] + sS[3][t];
    else
      v = sQ[0][t - 128] + sQ[1][t - 128] + sQ[2][t - 128] + sQ[3][t - 128];
    pstats[(size_t)blockIdx.x * 256 + t] = v;
  }
}

// ======================= BatchNorm =======================
__global__ __launch_bounds__(256) void bn_reduce_kernel(
    const float* __restrict__ pstats, float* __restrict__ stats, int nblk) {
  int t = threadIdx.x;
  float v = 0.f;
  for (int i = blockIdx.x; i < nblk; i += gridDim.x)
    v += pstats[(size_t)i * 256 + t];
  atomicAdd(&stats[t], v);
}

__global__ void bn_scale_kernel(const float* __restrict__ stats,
                                const float* __restrict__ gamma,
                                const float* __restrict__ beta,
                                float* __restrict__ sc) {
  int c = threadIdx.x;  // 128
  float mean = stats[c] / (float)N_NODES;
  float var = stats[DIM + c] / (float)N_NODES - mean * mean;
  float scale = gamma[c] * rsqrtf(var + 1e-5f);
  sc[c] = scale;
  sc[DIM + c] = beta[c] - mean * scale;
}

__global__ __launch_bounds__(256) void bn_apply_kernel(
    float* __restrict__ h, const float* __restrict__ sc) {
  size_t total = (size_t)N_NODES * DIM / 4;
  size_t stride = (size_t)gridDim.x * blockDim.x;
  for (size_t i = (size_t)blockIdx.x * blockDim.x + threadIdx.x; i < total;
       i += stride) {
    float4 v = reinterpret_cast<float4*>(h)[i];
    int c = (int)((i * 4) & 127);
    v.x = v.x * sc[c + 0] + sc[DIM + c + 0];
    v.y = v.y * sc[c + 1] + sc[DIM + c + 1];
    v.z = v.z * sc[c + 2] + sc[DIM + c + 2];
    v.w = v.w * sc[c + 3] + sc[DIM + c + 3];
    reinterpret_cast<float4*>(h)[i] = v;
  }
}

// ======================= Fallback kernels =======================
__global__ __launch_bounds__(256) void hist_kernel(const int* __restrict__ ei,
                                                   int* __restrict__ deg,
                                                   int E_) {
  int stride = gridDim.x * blockDim.x;
  for (int e = blockIdx.x * blockDim.x + threadIdx.x; e < E_; e += stride)
    atomicAdd(&deg[ei[E_ + e]], 1);
}

__global__ __launch_bounds__(256) void scan_block_kernel(
    const int* __restrict__ deg, int* __restrict__ offs,
    int* __restrict__ partials, int n) {
  const int tid = threadIdx.x;
  int g = blockIdx.x * 1024 + tid * 4;
  int v0 = (g + 0 < n) ? deg[g + 0] : 0;
  int v1 = (g + 1 < n) ? deg[g + 1] : 0;
  int v2 = (g + 2 < n) ? deg[g + 2] : 0;
  int v3 = (g + 3 < n) ? deg[g + 3] : 0;
  int tsum = v0 + v1 + v2 + v3;
  __shared__ int s[256];
  s[tid] = tsum;
  __syncthreads();
  for (int off = 1; off < 256; off <<= 1) {
    int t = (tid >= off) ? s[tid - off] : 0;
    __syncthreads();
    s[tid] += t;
    __syncthreads();
  }
  int excl = s[tid] - tsum;
  if (g + 0 < n) offs[g + 0] = excl;
  if (g + 1 < n) offs[g + 1] = excl + v0;
  if (g + 2 < n) offs[g + 2] = excl + v0 + v1;
  if (g + 3 < n) offs[g + 3] = excl + v0 + v1 + v2;
  if (tid == 255) partials[blockIdx.x] = s[255];
}

__global__ void scan_partials_kernel(int* __restrict__ partials, int nb) {
  const int tid = threadIdx.x;
  int v = (tid < nb) ? partials[tid] : 0;
  __shared__ int s[128];
  s[tid] = v;
  __syncthreads();
  for (int off = 1; off < 128; off <<= 1) {
    int t = (tid >= off) ? s[tid - off] : 0;
    __syncthreads();
    s[tid] += t;
    __syncthreads();
  }
  if (tid < nb) partials[tid] = s[tid] - v;
}

__global__ __launch_bounds__(256) void scan_add_kernel(
    int* __restrict__ offs, int* __restrict__ cursor,
    const int* __restrict__ partials, int n, int E_) {
  int g = blockIdx.x * blockDim.x + threadIdx.x;
  if (g < n) {
    int v = offs[g] + partials[g >> 10];
    offs[g] = v;
    cursor[g] = v;
  }
  if (g == 0) offs[n] = E_;
}

__global__ __launch_bounds__(256) void fill_kernel(const int* __restrict__ ei,
                                                   int* __restrict__ cursor,
                                                   int* __restrict__ csr,
                                                   int E_) {
  const int G = gridDim.x * blockDim.x;
  int g = blockIdx.x * blockDim.x + threadIdx.x;
  for (long long base = g; base < E_; base += (long long)G * 8) {
    int src[8], dst[8], pos[8];
#pragma unroll
    for (int k = 0; k < 8; ++k) {
      long long e = base + (long long)k * G;
      src[k] = (e < E_) ? ei[e] : -1;
      dst[k] = (e < E_) ? ei[E_ + e] : 0;
    }
#pragma unroll
    for (int k = 0; k < 8; ++k)
      if (src[k] >= 0) pos[k] = atomicAdd(&cursor[dst[k]], 1);
#pragma unroll
    for (int k = 0; k < 8; ++k)
      if (src[k] >= 0) csr[pos[k]] = src[k];
  }
}

__global__ __launch_bounds__(128) void gather_f32_kernel(
    const float* __restrict__ x, const int* __restrict__ offs,
    const int* __restrict__ csr, float* __restrict__ h) {
  int n = blockIdx.x;
  int c = threadIdx.x;
  int beg = offs[n], end = offs[n + 1];
  float acc = x[(size_t)n * DIM + c];
  for (int j = beg; j < end; ++j) acc += x[(size_t)csr[j] * DIM + c];
  h[(size_t)n * DIM + c] = acc;
}

__global__ __launch_bounds__(256) void scatter_kernel(
    const float* __restrict__ x, const int* __restrict__ ei,
    float* __restrict__ h, int E_) {
  long long total = (long long)E_ * 32;
  long long stride = (long long)gridDim.x * blockDim.x;
  for (long long idx = (long long)blockIdx.x * blockDim.x + threadIdx.x;
       idx < total; idx += stride) {
    int e = (int)(idx >> 5);
    int q = (int)(idx & 31);
    float4 v =
        *reinterpret_cast<const float4*>(x + (size_t)ei[e] * DIM + q * 4);
    float* p = h + (size_t)ei[E_ + e] * DIM + q * 4;
    atomicAdd(p + 0, v.x);
    atomicAdd(p + 1, v.y);
    atomicAdd(p + 2, v.z);
    atomicAdd(p + 3, v.w);
  }
}

__global__ __launch_bounds__(256) void add_x_kernel(const float* __restrict__ x,
                                                    float* __restrict__ h) {
  size_t total = (size_t)N_NODES * DIM / 4;
  size_t stride = (size_t)gridDim.x * blockDim.x;
  for (size_t i = (size_t)blockIdx.x * blockDim.x + threadIdx.x; i < total;
       i += stride) {
    float4 v = reinterpret_cast<float4*>(h)[i];
    float4 xv = reinterpret_cast<const float4*>(x)[i];
    v.x += xv.x; v.y += xv.y; v.z += xv.z; v.w += xv.w;
    reinterpret_cast<float4*>(h)[i] = v;
  }
}

__global__ __launch_bounds__(256) void mlp_valu_kernel(
    float* hbuf, const float* __restrict__ W1, const float* __restrict__ b1,
    const float* __restrict__ W2, const float* __restrict__ b2) {
  __shared__ float sW[DIM * DIM];
  __shared__ float sH[32][DIM];
  const int tid = threadIdx.x;
  const int col = tid & 127;
  const int rhalf = tid >> 7;
  const int row0 = blockIdx.x * 32;

  for (int i = tid; i < DIM * DIM; i += 256) sW[i] = W1[i];
  for (int i = tid; i < 32 * DIM; i += 256) {
    int r = i >> 7, c = i & 127;
    sH[r][c] = hbuf[(size_t)(row0 + r) * DIM + c];
  }
  __syncthreads();
  float acc[16];
  float bias = b1[col];
#pragma unroll
  for (int j = 0; j < 16; ++j) acc[j] = bias;
#pragma unroll 4
  for (int k = 0; k < DIM; ++k) {
    float w = sW[k * DIM + col];
#pragma unroll
    for (int j = 0; j < 16; ++j) acc[j] = fmaf(sH[2 * j + rhalf][k], w, acc[j]);
  }
  __syncthreads();
  for (int i = tid; i < DIM * DIM; i += 256) sW[i] = W2[i];
#pragma unroll
  for (int j = 0; j < 16; ++j) sH[2 * j + rhalf][col] = fmaxf(acc[j], 0.f);
  __syncthreads();
  float bias2 = b2[col];
#pragma unroll
  for (int j = 0; j < 16; ++j) acc[j] = bias2;
#pragma unroll 4
  for (int k = 0; k < DIM; ++k) {
    float w = sW[k * DIM + col];
#pragma unroll
    for (int j = 0; j < 16; ++j) acc[j] = fmaf(sH[2 * j + rhalf][k], w, acc[j]);
  }
#pragma unroll
  for (int j = 0; j < 16; ++j)
    hbuf[(size_t)(row0 + 2 * j + rhalf) * DIM + col] = fmaxf(acc[j], 0.f);
}

__global__ __launch_bounds__(256) void bn_stats_kernel(
    const float* __restrict__ h, float* __restrict__ stats) {
  int col = threadIdx.x & 127;
  int rsub = threadIdx.x >> 7;
  int rstep = gridDim.x * 2;
  float s = 0.f, ss = 0.f;
  for (int r = blockIdx.x * 2 + rsub; r < N_NODES; r += rstep) {
    float v = h[(size_t)r * DIM + col];
    s += v;
    ss += v * v;
  }
  __shared__ float ls[256], lss[256];
  ls[threadIdx.x] = s;
  lss[threadIdx.x] = ss;
  __syncthreads();
  if (threadIdx.x < 128) {
    atomicAdd(&stats[col], ls[threadIdx.x] + ls[threadIdx.x + 128]);
    atomicAdd(&stats[DIM + col], lss[threadIdx.x] + lss[threadIdx.x + 128]);
  }
}

extern "C" void kernel_launch(void* const* d_in, const int* in_sizes, int n_in,
                              void* d_out, int out_size, void* d_ws,
                              size_t ws_size, hipStream_t stream) {
  const float* x = (const float*)d_in[0];
  const int* ei = (const int*)d_in[1];
  const float* W1 = (const float*)d_in[3];
  const float* b1 = (const float*)d_in[4];
  const float* W2 = (const float*)d_in[5];
  const float* b2 = (const float*)d_in[6];
  const float* gamma = (const float*)d_in[7];
  const float* beta = (const float*)d_in[8];
  float* out = (float*)d_out;
  int E_ = in_sizes[1] / 2;

  // ---- full-path workspace layout (16B-aligned fields) ----
  const size_t XB_B = (size_t)N_NODES * DIM * 2;  // 25.6e6
  char* w = (char*)d_ws;
  size_t off = 0;
  u16* xb = (u16*)(w + off); off += XB_B;
  u16* hb = (u16*)(w + off); off += XB_B;
  u16* Wt1 = (u16*)(w + off); off += 32768;
  u16* Wt2 = (u16*)(w + off); off += 32768;
  u32* packed = (u32*)(w + off); off += (size_t)E_ * 4;      // doubles as csr
  int* offs = (int*)(w + off); off += ((size_t)N_NODES + 4) * 4;
  int* bcnt = (int*)(w + off); off += 1600;
  float* stats = (float*)(w + off); off += 3072;
  int* boffs = (int*)(w + off); off += 1600;
  int* gcur = (int*)(w + off); off += 1600;
  size_t need_full = off;
  float* pstats = (float*)xb;  // reuse xb after gather (dead by mlp time)

  // ---- CSR-only fallback layout ----
  int* f_offs = (int*)d_ws;
  int* f_cursor = f_offs + N_NODES + 1;
  int* f_partials = f_cursor + N_NODES;
  int* f_csr = f_partials + 128;
  float* f_stats = (float*)(f_csr + E_);
  size_t need_csr = ((size_t)2 * N_NODES + 129 + E_) * 4 + 3072;

  const int nScanBlocks = (N_NODES + 1023) / 1024;  // 98
  const int nEdgeBlocks = (E_ + 2047) / 2048;
  const int nPartBlocks = (E_ + PT_TILE - 1) / PT_TILE;
  const int nMlpBlocks = (N_NODES + 63) / 64;  // 1563

  if (ws_size >= need_full) {
    hipMemsetAsync(bcnt, 0, 1600 + 3072, stream);  // bcnt + stats
    prep_kernel<<<2688, 256, 0, stream>>>(x, xb, W1, Wt1, W2, Wt2, ei, bcnt,
                                          E_);
    bscan_kernel<<<1, 256, 0, stream>>>(bcnt, boffs, gcur);
    partition_kernel<<<nPartBlocks, PT_THR, 0, stream>>>(ei, gcur, packed, E_);
    bsort_kernel<<<NBUCK, 256, 0, stream>>>(packed, boffs, offs, E_);
    gather_bf16_kernel<<<N_NODES / 4, 256, 0, stream>>>(
        (const uint4*)xb, offs, (const int*)packed, (uint4*)hb);
    mlp_mfma_kernel<<<nMlpBlocks, 256, 0, stream>>>(hb, Wt1, Wt2, b1, b2, out,
                                                    pstats);
    bn_reduce_kernel<<<32, 256, 0, stream>>>(pstats, stats, nMlpBlocks);
    bn_scale_kernel<<<1, 128, 0, stream>>>(stats, gamma, beta, stats + 256);
    bn_apply_kernel<<<2048, 256, 0, stream>>>(out, stats + 256);
  } else if (ws_size >= need_csr) {
    hipMemsetAsync(f_cursor, 0, (size_t)N_NODES * sizeof(int), stream);
    hipMemsetAsync(f_stats, 0, 768 * sizeof(float), stream);
    hist_kernel<<<2048, 256, 0, stream>>>(ei, f_cursor, E_);
    scan_block_kernel<<<nScanBlocks, 256, 0, stream>>>(f_cursor, f_offs,
                                                       f_partials, N_NODES);
    scan_partials_kernel<<<1, 128, 0, stream>>>(f_partials, nScanBlocks);
    scan_add_kernel<<<(N_NODES + 255) / 256, 256, 0, stream>>>(
        f_offs, f_cursor, f_partials, N_NODES, E_);
    fill_kernel<<<nEdgeBlocks, 256, 0, stream>>>(ei, f_cursor, f_csr, E_);
    gather_f32_kernel<<<N_NODES, 128, 0, stream>>>(x, f_offs, f_csr, out);
    mlp_valu_kernel<<<(N_NODES + 31) / 32, 256, 0, stream>>>(out, W1, b1, W2,
                                                             b2);
    bn_stats_kernel<<<1024, 256, 0, stream>>>(out, f_stats);
    bn_scale_kernel<<<1, 128, 0, stream>>>(f_stats, gamma, beta, f_stats + 256);
    bn_apply_kernel<<<2048, 256, 0, stream>>>(out, f_stats + 256);
  } else {
    float* s2 = (float*)d_ws;
    hipMemsetAsync(out, 0, (size_t)N_NODES * DIM * sizeof(float), stream);
    hipMemsetAsync(s2, 0, 768 * sizeof(float), stream);
    scatter_kernel<<<4096, 256, 0, stream>>>(x, ei, out, E_);
    add_x_kernel<<<2048, 256, 0, stream>>>(x, out);
    mlp_valu_kernel<<<(N_NODES + 31) / 32, 256, 0, stream>>>(out, W1, b1, W2,
                                                             b2);
    bn_stats_kernel<<<1024, 256, 0, stream>>>(out, s2);
    bn_scale_kernel<<<1, 128, 0, stream>>>(s2, gamma, beta, s2 + 256);
    bn_apply_kernel<<<2048, 256, 0, stream>>>(out, s2 + 256);
  }
}